// Round 1
// baseline (2655.169 us; speedup 1.0000x reference)
//
#include <hip/hip_runtime.h>
#include <math.h>

#define HW    36864
#define IMG   192
#define NHEAD 2

// ---- ws layout (float offsets) ----
#define OFF_RS_QKV   0          // 384
#define OFF_B_QKV    384        // 384
#define OFF_RS_FFN   768        // 256
#define OFF_B_FFN    1024       // 256
#define OFF_SSQ      1280       // 1024   [zeroed]
#define OFF_AVG      2304       // 512    [zeroed]
#define OFF_MAXK     2816       // 512    [zeroed]
#define OFF_A        3328       // 32768
#define OFF_MU1      36096      // 147456
#define OFF_RSTD1    183552     // 147456
#define OFF_MU2      331008     // 147456
#define OFF_RSTD2    478464     // 147456
#define OFF_PART     625920     // 8*144*4096 = 4718592
#define OFF_QKV1     5344512    // 4*384*36864 = 56623104
// total 61967616 floats = 236 MB

__device__ __forceinline__ unsigned f2key(float f){
  unsigned b = __float_as_uint(f);
  return (b & 0x80000000u) ? ~b : (b | 0x80000000u);
}
__device__ __forceinline__ float key2f(unsigned k){
  return __uint_as_float((k & 0x80000000u) ? (k & 0x7fffffffu) : ~k);
}
__device__ __forceinline__ float gelu_f(float v){
  return 0.5f*v*(1.0f + erff(v*0.70710678118654752f));
}

// zero the atomic accumulators (ws re-poisoned 0xAA before every timed call)
__global__ __launch_bounds__(256) void k_init(float* ws){
  int t = blockIdx.x*256 + threadIdx.x;
  if (t < 2048) ws[OFF_SSQ + t] = 0.0f;   // ssq + avg + maxkey (contiguous)
}

// fold LN scale/bias into per-row GEMM constants
__global__ void k_prep(const float* wq, const float* wk, const float* wv,
                       const float* f1, const float* f2,
                       const float* liw, const float* lib,
                       const float* low, const float* lob, float* ws){
  int t = blockIdx.x*256 + threadIdx.x;
  if (t < 384){
    const float* W = (t < 128) ? wq : (t < 256) ? wk : wv;
    int r = t & 127;
    float rs = 0.f, bs = 0.f;
    for (int c = 0; c < 128; c++){ float w = W[r*128+c]; rs += w*liw[c]; bs += w*lib[c]; }
    ws[OFF_RS_QKV+t] = rs; ws[OFF_B_QKV+t] = bs;
  } else if (t < 640){
    int m = t - 384;
    const float* W = (m < 128) ? f1 : f2;
    int r = m & 127;
    float rs = 0.f, bs = 0.f;
    for (int c = 0; c < 128; c++){ float w = W[r*128+c]; rs += w*low[c]; bs += w*lob[c]; }
    ws[OFF_RS_FFN+m] = rs; ws[OFF_B_FFN+m] = bs;
  }
}

// per-pixel channel mean / rstd of x
__global__ __launch_bounds__(256) void k_stats(const float* __restrict__ x, float* __restrict__ ws){
  int g = blockIdx.x*256 + threadIdx.x;          // 147456
  int b = g / HW, p = g % HW;
  const float* xp = x + (size_t)b*128*HW + p;
  float s = 0.f, q = 0.f;
  #pragma unroll 8
  for (int c = 0; c < 128; c++){ float v = xp[(size_t)c*HW]; s += v; q += v*v; }
  float mu  = s * (1.f/128.f);
  float var = q * (1.f/128.f) - mu*mu;
  ws[OFF_MU1+g]   = mu;
  ws[OFF_RSTD1+g] = rsqrtf(var + 1e-5f);
}

// tiled fp32 GEMM:  dst[m][p] = epilogue( sum_k W'[m][k]*src[k][p] )
// LN folded: val = rstd[p]*(acc - mu[p]*rowsum[m]) + bias[m];  optional GELU
template<bool GELU>
__global__ __launch_bounds__(256) void k_gemm(
    const float* src, int src_bstride,
    const float* __restrict__ Wa, const float* __restrict__ Wb, const float* __restrict__ Wc,
    const float* __restrict__ lnw,
    const float* __restrict__ rowsum, const float* __restrict__ bias,
    const float* __restrict__ mu, const float* __restrict__ rstd,
    float* dst, int dst_coff)
{
  __shared__ float As[16][128];
  __shared__ float Bs[16][128];
  int t  = threadIdx.x;
  int m0 = blockIdx.x*128, p0 = blockIdx.y*128, b = blockIdx.z;
  const float* W = (m0 == 0) ? Wa : (m0 == 128) ? Wb : Wc;
  int tm = (t>>4)<<3, tn = (t&15)<<3;
  int lm = t>>1, lk = (t&1)<<3;
  int bk = t>>4, bp = (t&15)<<3;
  float acc[8][8] = {};
  const float* mup = mu   + (size_t)b*HW + p0;
  const float* rsp = rstd + (size_t)b*HW + p0;

  for (int kt = 0; kt < 8; kt++){
    int k0 = kt*16;
    {
      const float* wrow = W + (size_t)lm*128 + k0 + lk;
      #pragma unroll
      for (int u = 0; u < 8; u++) As[lk+u][lm] = wrow[u] * lnw[k0+lk+u];
    }
    {
      const float* srow = src + ((size_t)(b*src_bstride + k0 + bk))*HW + p0 + bp;
      float4 v0 = *(const float4*)srow;
      float4 v1 = *(const float4*)(srow+4);
      *(float4*)&Bs[bk][bp]   = v0;
      *(float4*)&Bs[bk][bp+4] = v1;
    }
    __syncthreads();
    #pragma unroll
    for (int k = 0; k < 16; k++){
      float4 a0 = *(const float4*)&As[k][tm];
      float4 a1 = *(const float4*)&As[k][tm+4];
      float4 b0 = *(const float4*)&Bs[k][tn];
      float4 b1 = *(const float4*)&Bs[k][tn+4];
      float av[8] = {a0.x,a0.y,a0.z,a0.w,a1.x,a1.y,a1.z,a1.w};
      float bv[8] = {b0.x,b0.y,b0.z,b0.w,b1.x,b1.y,b1.z,b1.w};
      #pragma unroll
      for (int i = 0; i < 8; i++)
        #pragma unroll
        for (int j = 0; j < 8; j++) acc[i][j] += av[i]*bv[j];
    }
    __syncthreads();
  }

  float muv[8], rsv[8];
  #pragma unroll
  for (int j = 0; j < 8; j++){ muv[j] = mup[tn+j]; rsv[j] = rsp[tn+j]; }
  #pragma unroll
  for (int i = 0; i < 8; i++){
    int m = m0 + tm + i;
    float rsum = rowsum[m], bv = bias[m];
    float* drow = dst + ((size_t)(b*384 + dst_coff + m))*HW + p0 + tn;
    float vals[8];
    #pragma unroll
    for (int j = 0; j < 8; j++){
      float v = rsv[j]*(acc[i][j] - muv[j]*rsum) + bv;
      if (GELU) v = gelu_f(v);
      vals[j] = v;
    }
    *(float4*)drow     = make_float4(vals[0],vals[1],vals[2],vals[3]);
    *(float4*)(drow+4) = make_float4(vals[4],vals[5],vals[6],vals[7]);
  }
}

// attn partials: per (b,head,chunk of 256 px): 64x64 = sum_p dw(q1)[c][p]*dw(k1)[d][p]
// dw3x3 applied on the fly; also accumulates sum-of-squares for L2 norms.
__global__ __launch_bounds__(256) void k_attn(const float* qkv1,
                                              const float* __restrict__ wqdw,
                                              const float* __restrict__ wkdw,
                                              float* __restrict__ part,
                                              float* __restrict__ ssq)
{
  __shared__ float q_lds[64][72];
  __shared__ float k_lds[64][72];
  __shared__ float wq_l[64][9], wk_l[64][9];
  __shared__ float ss[128];
  int t = threadIdx.x;
  int chunk = blockIdx.x, h = blockIdx.y, b = blockIdx.z;
  for (int e = t; e < 576; e += 256) wq_l[e/9][e%9] = wqdw[(h*64 + e/9)*9 + e%9];
  for (int e = t; e < 576; e += 256) wk_l[e/9][e%9] = wkdw[(h*64 + e/9)*9 + e%9];
  if (t < 128) ss[t] = 0.f;
  int lane = t & 63, wvid = t >> 6;
  int tc = (t>>4)<<2, td = (t&15)<<2;
  float acc[4][4] = {};
  const float* qbase = qkv1 + ((size_t)(b*384 + h*64))*HW;
  const float* kbase = qkv1 + ((size_t)(b*384 + 128 + h*64))*HW;

  for (int st = 0; st < 4; st++){
    int p0 = chunk*256 + st*64;           // 64-aligned -> inside one image row
    int hh = p0 / IMG, w0 = p0 % IMG;
    __syncthreads();
    // stage q
    for (int i = 0; i < 16; i++){
      int c = i*4 + wvid;
      const float* src = qbase + (size_t)c*HW;
      float v = 0.f;
      #pragma unroll
      for (int dy = -1; dy <= 1; dy++){
        int hy = hh + dy;
        if (hy >= 0 && hy < IMG){
          const float* rp = src + hy*IMG;
          #pragma unroll
          for (int dx = -1; dx <= 1; dx++){
            int wx = w0 + lane + dx;
            if (wx >= 0 && wx < IMG) v += rp[wx]*wq_l[c][(dy+1)*3+dx+1];
          }
        }
      }
      q_lds[lane][c] = v;
      float s2 = v*v;
      #pragma unroll
      for (int off = 32; off; off >>= 1) s2 += __shfl_xor(s2, off);
      if (lane == 0) ss[c] += s2;
    }
    // stage k
    for (int i = 0; i < 16; i++){
      int c = i*4 + wvid;
      const float* src = kbase + (size_t)c*HW;
      float v = 0.f;
      #pragma unroll
      for (int dy = -1; dy <= 1; dy++){
        int hy = hh + dy;
        if (hy >= 0 && hy < IMG){
          const float* rp = src + hy*IMG;
          #pragma unroll
          for (int dx = -1; dx <= 1; dx++){
            int wx = w0 + lane + dx;
            if (wx >= 0 && wx < IMG) v += rp[wx]*wk_l[c][(dy+1)*3+dx+1];
          }
        }
      }
      k_lds[lane][c] = v;
      float s2 = v*v;
      #pragma unroll
      for (int off = 32; off; off >>= 1) s2 += __shfl_xor(s2, off);
      if (lane == 0) ss[64+c] += s2;
    }
    __syncthreads();
    for (int p = 0; p < 64; p++){
      float4 q4 = *(const float4*)&q_lds[p][tc];
      float4 k4 = *(const float4*)&k_lds[p][td];
      float qa[4] = {q4.x,q4.y,q4.z,q4.w};
      float ka[4] = {k4.x,k4.y,k4.z,k4.w};
      #pragma unroll
      for (int i = 0; i < 4; i++)
        #pragma unroll
        for (int j = 0; j < 4; j++) acc[i][j] += qa[i]*ka[j];
    }
  }
  __syncthreads();
  float* pp = part + ((size_t)((b*2+h)*144 + chunk))*4096;
  #pragma unroll
  for (int i = 0; i < 4; i++)
    *(float4*)&pp[(tc+i)*64 + td] = make_float4(acc[i][0],acc[i][1],acc[i][2],acc[i][3]);
  if (t < 128){
    int idx = (t < 64) ? (b*256 + h*64 + t) : (b*256 + 128 + h*64 + (t-64));
    atomicAdd(&ssq[idx], ss[t]);
  }
}

// reduce partials, apply L2-norm + scale, emit attn_weight (pre-softmax) and a (softmax)
__global__ __launch_bounds__(256) void k_softmax(const float* __restrict__ part,
                                                 const float* __restrict__ ssq,
                                                 const float* __restrict__ scale,
                                                 float* __restrict__ ws_a,
                                                 float* __restrict__ out)
{
  __shared__ float attn_s[4096];
  __shared__ float rnq[64], rnk[64];
  int t = threadIdx.x;
  int h = blockIdx.x, b = blockIdx.y;
  const float* pp = part + ((size_t)(b*2+h))*144*4096;
  for (int e = t; e < 4096; e += 256){
    float s = 0.f;
    for (int ch = 0; ch < 144; ch++) s += pp[(size_t)ch*4096 + e];
    attn_s[e] = s;
  }
  if (t < 64)       rnq[t]    = 1.0f/fmaxf(sqrtf(ssq[b*256 + h*64 + t]), 1e-12f);
  else if (t < 128) rnk[t-64] = 1.0f/fmaxf(sqrtf(ssq[b*256 + 128 + h*64 + (t-64)]), 1e-12f);
  __syncthreads();
  if (t < 64){
    int c = t;
    float rq = rnq[c]*scale[h];
    float vals[64], vmax = -1e30f;
    for (int d = 0; d < 64; d++){
      float v = attn_s[c*64+d]*rq*rnk[d];
      vals[d] = v; vmax = fmaxf(vmax, v);
    }
    float* aw = out + 512 + ((size_t)(b*128 + h*64 + c))*64;
    for (int d = 0; d < 64; d++) aw[d] = vals[d];
    float se = 0.f;
    for (int d = 0; d < 64; d++){ float e = expf(vals[d]-vmax); vals[d] = e; se += e; }
    float inv = 1.0f/se;
    float* ar = ws_a + ((size_t)((b*2+h)*64 + c))*64;
    for (int d = 0; d < 64; d++) ar[d] = vals[d]*inv;
  }
}

// out = a @ dw(v1)  (block-diagonal per head) + per-pixel LN stats of out
__global__ __launch_bounds__(256) void k_av(const float* __restrict__ ws_a,
                                            const float* qkv1,
                                            const float* __restrict__ wvdw,
                                            float* dst, float* __restrict__ mu2,
                                            float* __restrict__ rstd2)
{
  __shared__ float a_lds[128][70];
  __shared__ float v_lds[128][64];
  __shared__ float wv_l[128][9];
  __shared__ float px_s[64], px_q[64];
  int t = threadIdx.x;
  int pt = blockIdx.x, b = blockIdx.y;
  int p0 = pt*64;
  int hh = p0 / IMG, w0 = p0 % IMG;
  int lane = t & 63, wvid = t >> 6;
  for (int e = t; e < 1152; e += 256) wv_l[e/9][e%9] = wvdw[e];
  if (t < 64){ px_s[t] = 0.f; px_q[t] = 0.f; }
  __syncthreads();
  const float* ab = ws_a + (size_t)b*128*64;
  for (int i = 0; i < 32; i++){
    int idx = i*256 + t;
    a_lds[idx>>6][idx&63] = ab[idx];
  }
  const float* vb = qkv1 + ((size_t)(b*384 + 256))*HW;
  for (int i = 0; i < 32; i++){
    int dg = i*4 + wvid;
    const float* src = vb + (size_t)dg*HW;
    float v = 0.f;
    #pragma unroll
    for (int dy = -1; dy <= 1; dy++){
      int hy = hh + dy;
      if (hy >= 0 && hy < IMG){
        const float* rp = src + hy*IMG;
        #pragma unroll
        for (int dx = -1; dx <= 1; dx++){
          int wx = w0 + lane + dx;
          if (wx >= 0 && wx < IMG) v += rp[wx]*wv_l[dg][(dy+1)*3+dx+1];
        }
      }
    }
    v_lds[dg][lane] = v;
  }
  __syncthreads();
  int tm = (t>>4)<<3, tp = (t&15)<<2;
  int hd = tm >> 6;
  float acc[8][4] = {};
  for (int d = 0; d < 64; d++){
    float4 v4 = *(const float4*)&v_lds[hd*64+d][tp];
    float vv[4] = {v4.x,v4.y,v4.z,v4.w};
    float av[8];
    #pragma unroll
    for (int i = 0; i < 8; i++) av[i] = a_lds[tm+i][d];
    #pragma unroll
    for (int i = 0; i < 8; i++)
      #pragma unroll
      for (int j = 0; j < 4; j++) acc[i][j] += av[i]*vv[j];
  }
  #pragma unroll
  for (int i = 0; i < 8; i++){
    float* drow = dst + ((size_t)(b*384 + tm+i))*HW + p0 + tp;
    *(float4*)drow = make_float4(acc[i][0],acc[i][1],acc[i][2],acc[i][3]);
  }
  #pragma unroll
  for (int j = 0; j < 4; j++){
    float s = 0.f, q = 0.f;
    #pragma unroll
    for (int i = 0; i < 8; i++){ s += acc[i][j]; q += acc[i][j]*acc[i][j]; }
    atomicAdd(&px_s[tp+j], s);
    atomicAdd(&px_q[tp+j], q);
  }
  __syncthreads();
  if (t < 64){
    float mu  = px_s[t]*(1.f/128.f);
    float var = px_q[t]*(1.f/128.f) - mu*mu;
    mu2[(size_t)b*HW + p0 + t]   = mu;
    rstd2[(size_t)b*HW + p0 + t] = rsqrtf(var + 1e-5f);
  }
}

// z = gelu(dw3x3(g)); ffn = f_out @ z; avg/max pool per (b, out-channel)
__global__ __launch_bounds__(256) void k_ffn2(const float* g,
                                              const float* __restrict__ fdw1,
                                              const float* __restrict__ fdw2,
                                              const float* __restrict__ fout,
                                              float* __restrict__ avg,
                                              unsigned* __restrict__ maxk)
{
  __shared__ float z_lds[256][36];
  __shared__ float f_lds[64][129];
  __shared__ float osum[128];
  __shared__ unsigned okey[128];
  int t = threadIdx.x;
  int pt = blockIdx.x, b = blockIdx.y;
  int p0 = pt*32;
  int hh = p0 / IMG, w0 = p0 % IMG;
  if (t < 128){ osum[t] = 0.f; okey[t] = 0u; }
  const float* gb = g + ((size_t)(b*384 + 128))*HW;
  for (int it = 0; it < 32; it++){
    int idx = it*256 + t;
    int ich = idx >> 5, p = idx & 31;
    const float* wdw = (ich < 128) ? (fdw1 + (size_t)ich*9) : (fdw2 + (size_t)(ich-128)*9);
    const float* src = gb + (size_t)ich*HW;
    float v = 0.f;
    #pragma unroll
    for (int dy = -1; dy <= 1; dy++){
      int hy = hh + dy;
      if (hy >= 0 && hy < IMG){
        const float* rp = src + hy*IMG;
        #pragma unroll
        for (int dx = -1; dx <= 1; dx++){
          int wx = w0 + p + dx;
          if (wx >= 0 && wx < IMG) v += rp[wx]*wdw[(dy+1)*3+dx+1];
        }
      }
    }
    z_lds[ich][p] = gelu_f(v);
  }
  int to = (t>>2)<<1;
  int po = (t&3)<<3;
  float acc[2][8] = {};
  for (int kc = 0; kc < 4; kc++){
    __syncthreads();
    for (int r = 0; r < 32; r++){
      int o = r*4 + (t>>6);
      int i = t & 63;
      f_lds[i][o] = fout[(size_t)o*256 + kc*64 + i];
    }
    __syncthreads();
    #pragma unroll 4
    for (int k = 0; k < 64; k++){
      float f0 = f_lds[k][to], f1v = f_lds[k][to+1];
      float4 z0 = *(const float4*)&z_lds[kc*64+k][po];
      float4 z1 = *(const float4*)&z_lds[kc*64+k][po+4];
      float zv[8] = {z0.x,z0.y,z0.z,z0.w,z1.x,z1.y,z1.z,z1.w};
      #pragma unroll
      for (int j = 0; j < 8; j++){ acc[0][j] += f0*zv[j]; acc[1][j] += f1v*zv[j]; }
    }
  }
  #pragma unroll
  for (int i2 = 0; i2 < 2; i2++){
    float s = 0.f, mx = -1e30f;
    #pragma unroll
    for (int j = 0; j < 8; j++){ s += acc[i2][j]; mx = fmaxf(mx, acc[i2][j]); }
    atomicAdd(&osum[to+i2], s);
    atomicMax(&okey[to+i2], f2key(mx));
  }
  __syncthreads();
  if (t < 128){
    atomicAdd(&avg[b*128+t], osum[t]);
    atomicMax(&maxk[b*128+t], okey[t]);
  }
}

// ChannelGate MLP + sigmoid
__global__ __launch_bounds__(128) void k_gate(const float* __restrict__ avg,
                                              const unsigned* __restrict__ maxk,
                                              const float* __restrict__ w1, const float* __restrict__ b1,
                                              const float* __restrict__ w2, const float* __restrict__ b2,
                                              float* __restrict__ out)
{
  __shared__ float ap[128], mp[128], h1a[8], h1m[8];
  int t = threadIdx.x, b = blockIdx.x;
  ap[t] = avg[b*128+t]*(1.0f/36864.0f);
  mp[t] = key2f(maxk[b*128+t]);
  __syncthreads();
  if (t < 8){
    float sa = b1[t], sm = b1[t];
    for (int c = 0; c < 128; c++){ float w = w1[t*128+c]; sa += w*ap[c]; sm += w*mp[c]; }
    h1a[t] = fmaxf(sa, 0.f); h1m[t] = fmaxf(sm, 0.f);
  }
  __syncthreads();
  float y = 2.0f*b2[t];
  for (int r = 0; r < 8; r++) y += w2[t*8+r]*(h1a[r]+h1m[r]);
  out[b*128+t] = 1.0f/(1.0f+expf(-y));
}

extern "C" void kernel_launch(void* const* d_in, const int* in_sizes, int n_in,
                              void* d_out, int out_size, void* d_ws, size_t ws_size,
                              hipStream_t stream)
{
  const float* x        = (const float*)d_in[0];
  const float* ln_in_w  = (const float*)d_in[1];
  const float* ln_in_b  = (const float*)d_in[2];
  const float* wq_pw    = (const float*)d_in[3];
  const float* wq_dw    = (const float*)d_in[4];
  const float* wk_pw    = (const float*)d_in[5];
  const float* wk_dw    = (const float*)d_in[6];
  const float* wv_pw    = (const float*)d_in[7];
  const float* wv_dw    = (const float*)d_in[8];
  const float* scale    = (const float*)d_in[9];
  const float* ln_out_w = (const float*)d_in[10];
  const float* ln_out_b = (const float*)d_in[11];
  const float* f1_pw    = (const float*)d_in[12];
  const float* f1_dw    = (const float*)d_in[13];
  const float* f2_pw    = (const float*)d_in[14];
  const float* f2_dw    = (const float*)d_in[15];
  const float* f_out    = (const float*)d_in[16];
  const float* g_w1     = (const float*)d_in[17];
  const float* g_b1     = (const float*)d_in[18];
  const float* g_w2     = (const float*)d_in[19];
  const float* g_b2     = (const float*)d_in[20];
  float* ws  = (float*)d_ws;
  float* out = (float*)d_out;

  k_init<<<dim3(8), dim3(256), 0, stream>>>(ws);
  k_prep<<<dim3(3), dim3(256), 0, stream>>>(wq_pw, wk_pw, wv_pw, f1_pw, f2_pw,
                                            ln_in_w, ln_in_b, ln_out_w, ln_out_b, ws);
  k_stats<<<dim3(576), dim3(256), 0, stream>>>(x, ws);
  // QKV 1x1 with LN folded -> qkv1 (pre-dw)
  k_gemm<false><<<dim3(3,288,4), dim3(256), 0, stream>>>(
      x, 128, wq_pw, wk_pw, wv_pw, ln_in_w,
      ws+OFF_RS_QKV, ws+OFF_B_QKV, ws+OFF_MU1, ws+OFF_RSTD1,
      ws+OFF_QKV1, 0);
  // attn raw dots (dw on the fly) + sumsq
  k_attn<<<dim3(144,2,4), dim3(256), 0, stream>>>(
      ws+OFF_QKV1, wq_dw, wk_dw, ws+OFF_PART, ws+OFF_SSQ);
  // reduce + normalize + attn_weight + softmax
  k_softmax<<<dim3(2,4), dim3(256), 0, stream>>>(
      ws+OFF_PART, ws+OFF_SSQ, scale, ws+OFF_A, out);
  // out = a @ dw(v1), + LN stats (writes into qkv1 ch 0..127 slots)
  k_av<<<dim3(576,4), dim3(256), 0, stream>>>(
      ws+OFF_A, ws+OFF_QKV1, wv_dw, ws+OFF_QKV1, ws+OFF_MU2, ws+OFF_RSTD2);
  // FFN 1x1 + LN folded + GELU -> g (qkv1 ch 128..383 slots)
  k_gemm<true><<<dim3(2,288,4), dim3(256), 0, stream>>>(
      ws+OFF_QKV1, 384, f1_pw, f2_pw, f2_pw, ln_out_w,
      ws+OFF_RS_FFN, ws+OFF_B_FFN, ws+OFF_MU2, ws+OFF_RSTD2,
      ws+OFF_QKV1, 128);
  // dw + gelu + f_out GEMM + pools
  k_ffn2<<<dim3(1152,4), dim3(256), 0, stream>>>(
      ws+OFF_QKV1, f1_dw, f2_dw, f_out, ws+OFF_AVG, (unsigned*)(ws+OFF_MAXK));
  k_gate<<<dim3(4), dim3(128), 0, stream>>>(
      ws+OFF_AVG, (const unsigned*)(ws+OFF_MAXK), g_w1, g_b1, g_w2, g_b2, out);

  (void)in_sizes; (void)n_in; (void)out_size; (void)ws_size;
}

// Round 2
// 988.203 us; speedup vs baseline: 2.6869x; 2.6869x over previous
//
#include <hip/hip_runtime.h>
#include <math.h>

#define HW    36864
#define IMG   192

// ---- ws layout (float offsets) ----
#define OFF_RS_QKV   0          // 384 (q,k rows 0-255; v rows 256-383)
#define OFF_B_QKV    384        // 384
#define OFF_RS_FFN   768        // 256
#define OFF_B_FFN    1024       // 256
#define OFF_SSQ      1280       // 1024 [zeroed]
#define OFF_AVG      2304       // 512  [zeroed]
#define OFF_MAXK     2816       // 512  [zeroed]
#define OFF_A        3328       // 32768 softmax probs
#define OFF_MU1      36096      // 147456
#define OFF_RSTD1    183552     // 147456
#define OFF_MU2      331008     // 147456
#define OFF_RSTD2    478464     // 147456
#define OFF_PART     625920     // 8*64*4096 = 2097152
#define OFF_FT       2723072    // 32768 (f_out transposed [256k][128oc])
#define OFF_BUF1     2755840    // 4*384*36864 = 56623104 -> end 59378944 (237.5 MB)

__device__ __forceinline__ unsigned f2key(float f){
  unsigned b = __float_as_uint(f);
  return (b & 0x80000000u) ? ~b : (b | 0x80000000u);
}
__device__ __forceinline__ float key2f(unsigned k){
  return __uint_as_float((k & 0x80000000u) ? (k & 0x7fffffffu) : ~k);
}
__device__ __forceinline__ float gelu_f(float v){
  return 0.5f*v*(1.0f + erff(v*0.70710678118654752f));
}

__global__ __launch_bounds__(256) void k_init(float* ws){
  int t = blockIdx.x*256 + threadIdx.x;
  if (t < 2048) ws[OFF_SSQ + t] = 0.0f;   // ssq + avg + maxkey
}

// LN fold constants + f_out transpose
__global__ void k_prep(const float* wq, const float* wk, const float* wv,
                       const float* f1, const float* f2, const float* fo,
                       const float* liw, const float* lib,
                       const float* low, const float* lob, float* ws){
  int t = blockIdx.x*256 + threadIdx.x;
  if (t < 384){
    const float* W = (t < 128) ? wq : (t < 256) ? wk : wv;
    int r = t & 127;
    float rs = 0.f, bs = 0.f;
    for (int c = 0; c < 128; c++){ float w = W[r*128+c]; rs += w*liw[c]; bs += w*lib[c]; }
    ws[OFF_RS_QKV+t] = rs; ws[OFF_B_QKV+t] = bs;
  } else if (t < 640){
    int m = t - 384;
    const float* W = (m < 128) ? f1 : f2;
    int r = m & 127;
    float rs = 0.f, bs = 0.f;
    for (int c = 0; c < 128; c++){ float w = W[r*128+c]; rs += w*low[c]; bs += w*lob[c]; }
    ws[OFF_RS_FFN+m] = rs; ws[OFF_B_FFN+m] = bs;
  }
  int ft = t - 640;
  if (ft >= 0 && ft < 32768){
    int kk = ft >> 7, oc = ft & 127;
    ws[OFF_FT + ft] = fo[oc*256 + kk];
  }
}

// per-pixel channel mean / rstd of x (4 px per thread, float4)
__global__ __launch_bounds__(256) void k_stats(const float* __restrict__ x, float* __restrict__ ws){
  int t = threadIdx.x, b = blockIdx.y;
  int p0 = blockIdx.x*1024 + t*4;
  const float* xp = x + (size_t)b*128*HW + p0;
  float s[4] = {}, q[4] = {};
  #pragma unroll 4
  for (int c = 0; c < 128; c++){
    float4 v = *(const float4*)(xp + (size_t)c*HW);
    float vv[4] = {v.x,v.y,v.z,v.w};
    #pragma unroll
    for (int j = 0; j < 4; j++){ s[j] += vv[j]; q[j] += vv[j]*vv[j]; }
  }
  float mu[4], rs[4];
  #pragma unroll
  for (int j = 0; j < 4; j++){
    mu[j] = s[j]*(1.f/128.f);
    rs[j] = rsqrtf(q[j]*(1.f/128.f) - mu[j]*mu[j] + 1e-5f);
  }
  size_t g = (size_t)b*HW + p0;
  *(float4*)&ws[OFF_MU1 + g]   = make_float4(mu[0],mu[1],mu[2],mu[3]);
  *(float4*)&ws[OFF_RSTD1 + g] = make_float4(rs[0],rs[1],rs[2],rs[3]);
}

// tiled fp32 GEMM with LN folded epilogue (+optional GELU)
template<bool GELU>
__global__ __launch_bounds__(256) void k_gemm(
    const float* src, int src_bstride,
    const float* __restrict__ Wa, const float* __restrict__ Wb, const float* __restrict__ Wc,
    const float* __restrict__ lnw,
    const float* __restrict__ rowsum, const float* __restrict__ bias,
    const float* __restrict__ mu, const float* __restrict__ rstd,
    float* dst, int dst_coff)
{
  __shared__ float As[16][128];
  __shared__ float Bs[16][128];
  int t  = threadIdx.x;
  int m0 = blockIdx.x*128, p0 = blockIdx.y*128, b = blockIdx.z;
  const float* W = (m0 == 0) ? Wa : (m0 == 128) ? Wb : Wc;
  int tm = (t>>4)<<3, tn = (t&15)<<3;
  int lm = t>>1, lk = (t&1)<<3;
  int bk = t>>4, bp = (t&15)<<3;
  float acc[8][8] = {};
  const float* mup = mu   + (size_t)b*HW + p0;
  const float* rsp = rstd + (size_t)b*HW + p0;

  for (int kt = 0; kt < 8; kt++){
    int k0 = kt*16;
    {
      const float* wrow = W + (size_t)lm*128 + k0 + lk;
      #pragma unroll
      for (int u = 0; u < 8; u++) As[lk+u][lm] = wrow[u] * lnw[k0+lk+u];
    }
    {
      const float* srow = src + ((size_t)(b*src_bstride + k0 + bk))*HW + p0 + bp;
      float4 v0 = *(const float4*)srow;
      float4 v1 = *(const float4*)(srow+4);
      *(float4*)&Bs[bk][bp]   = v0;
      *(float4*)&Bs[bk][bp+4] = v1;
    }
    __syncthreads();
    #pragma unroll
    for (int k = 0; k < 16; k++){
      float4 a0 = *(const float4*)&As[k][tm];
      float4 a1 = *(const float4*)&As[k][tm+4];
      float4 b0 = *(const float4*)&Bs[k][tn];
      float4 b1 = *(const float4*)&Bs[k][tn+4];
      float av[8] = {a0.x,a0.y,a0.z,a0.w,a1.x,a1.y,a1.z,a1.w};
      float bv[8] = {b0.x,b0.y,b0.z,b0.w,b1.x,b1.y,b1.z,b1.w};
      #pragma unroll
      for (int i = 0; i < 8; i++)
        #pragma unroll
        for (int j = 0; j < 8; j++) acc[i][j] += av[i]*bv[j];
    }
    __syncthreads();
  }

  float muv[8], rsv[8];
  #pragma unroll
  for (int j = 0; j < 8; j++){ muv[j] = mup[tn+j]; rsv[j] = rsp[tn+j]; }
  #pragma unroll
  for (int i = 0; i < 8; i++){
    int m = m0 + tm + i;
    float rsum = rowsum[m], bv = bias[m];
    float* drow = dst + ((size_t)(b*384 + dst_coff + m))*HW + p0 + tn;
    float vals[8];
    #pragma unroll
    for (int j = 0; j < 8; j++){
      float v = rsv[j]*(acc[i][j] - muv[j]*rsum) + bv;
      if (GELU) v = gelu_f(v);
      vals[j] = v;
    }
    *(float4*)drow     = make_float4(vals[0],vals[1],vals[2],vals[3]);
    *(float4*)(drow+4) = make_float4(vals[4],vals[5],vals[6],vals[7]);
  }
}

// streaming depthwise 3x3 (pad 1): one (batch, channel, 8-row band) per block.
// optional GELU after, optional per-channel sum-of-squares accumulation.
template<bool GELU, bool SSQ>
__global__ __launch_bounds__(256) void k_dw(const float* __restrict__ src,
                                            const float* __restrict__ wdw,
                                            float* __restrict__ dst,
                                            float* __restrict__ ssq, int ssq_off){
  __shared__ float rows[10][194];
  __shared__ float wred[4];
  int t = threadIdx.x;
  int band = blockIdx.x, c = blockIdx.y, b = blockIdx.z;
  const float* sp = src + ((size_t)(b*384 + c))*HW;
  float w[9];
  #pragma unroll
  for (int j = 0; j < 9; j++) w[j] = wdw[c*9 + j];
  int r0 = band*8;
  for (int e = t; e < 1920; e += 256){
    int r = e/192, cc = e - r*192;
    int gr = r0 + r - 1;
    rows[r][cc+1] = (gr >= 0 && gr < IMG) ? sp[gr*IMG + cc] : 0.f;
  }
  if (t < 20) rows[t>>1][(t&1)*193] = 0.f;
  __syncthreads();
  float s2 = 0.f;
  float* dp = dst + ((size_t)(b*384 + c))*HW + r0*IMG;
  #pragma unroll
  for (int i = 0; i < 6; i++){
    int px = i*256 + t;
    int r = px/192, cc = px - r*192;
    float v = 0.f;
    #pragma unroll
    for (int dy = 0; dy < 3; dy++)
      #pragma unroll
      for (int dx = 0; dx < 3; dx++)
        v += rows[r+dy][cc+dx] * w[dy*3+dx];
    if (GELU) v = gelu_f(v);
    dp[px] = v;
    if (SSQ) s2 += v*v;
  }
  if (SSQ){
    #pragma unroll
    for (int off = 32; off; off >>= 1) s2 += __shfl_xor(s2, off);
    if ((t & 63) == 0) wred[t>>6] = s2;
    __syncthreads();
    if (t == 0) atomicAdd(&ssq[b*256 + ssq_off + c], wred[0]+wred[1]+wred[2]+wred[3]);
  }
}

// split-K 64x64 gram: part[bh][chunk] = sum over 576 px of q2[c][p]*k2[d][p]
__global__ __launch_bounds__(256,4) void k_qk(const float* __restrict__ buf,
                                              float* __restrict__ part){
  __shared__ float qs[64][68];
  __shared__ float ks[64][68];
  int t = threadIdx.x;
  int chunk = blockIdx.x, h = blockIdx.y, b = blockIdx.z;
  int tc = (t>>4)<<2, td = (t&15)<<2;
  int c = t>>2, pq = (t&3)<<4;
  const float* qp = buf + ((size_t)(b*384 + 256 + h*64 + c))*HW + chunk*576 + pq;
  const float* kp = buf + ((size_t)(b*384 +       h*64 + c))*HW + chunk*576 + pq;
  float acc[4][4] = {};
  for (int st = 0; st < 9; st++){
    __syncthreads();
    #pragma unroll
    for (int u = 0; u < 4; u++){
      float4 qv = *(const float4*)(qp + st*64 + u*4);
      float4 kv = *(const float4*)(kp + st*64 + u*4);
      int p = pq + u*4;
      qs[p+0][c] = qv.x; qs[p+1][c] = qv.y; qs[p+2][c] = qv.z; qs[p+3][c] = qv.w;
      ks[p+0][c] = kv.x; ks[p+1][c] = kv.y; ks[p+2][c] = kv.z; ks[p+3][c] = kv.w;
    }
    __syncthreads();
    #pragma unroll 4
    for (int p = 0; p < 64; p++){
      float4 q4 = *(const float4*)&qs[p][tc];
      float4 k4 = *(const float4*)&ks[p][td];
      float qa[4] = {q4.x,q4.y,q4.z,q4.w};
      float ka[4] = {k4.x,k4.y,k4.z,k4.w};
      #pragma unroll
      for (int i = 0; i < 4; i++)
        #pragma unroll
        for (int j = 0; j < 4; j++) acc[i][j] += qa[i]*ka[j];
    }
  }
  float* pp = part + ((size_t)((b*2+h)*64 + chunk))*4096;
  #pragma unroll
  for (int i = 0; i < 4; i++)
    *(float4*)&pp[(tc+i)*64 + td] = make_float4(acc[i][0],acc[i][1],acc[i][2],acc[i][3]);
}

// reduce partials + L2-normalize + scale -> attn_weight (out) and softmax probs (ws_a)
__global__ __launch_bounds__(256) void k_softmax(const float* __restrict__ part,
                                                 const float* __restrict__ ssq,
                                                 const float* __restrict__ scale,
                                                 float* __restrict__ ws_a,
                                                 float* __restrict__ out)
{
  __shared__ float red[8][64];
  __shared__ float rnk[64];
  int t = threadIdx.x;
  int c0 = blockIdx.x*8, h = blockIdx.y, b = blockIdx.z;
  int bh = b*2 + h;
  const float* pp = part + (size_t)bh*64*4096;
  for (int e = t; e < 512; e += 256){
    int c = e>>6, d = e&63;
    float s = 0.f;
    for (int ch = 0; ch < 64; ch++) s += pp[(size_t)ch*4096 + (c0+c)*64 + d];
    red[c][d] = s;
  }
  if (t < 64) rnk[t] = 1.0f/fmaxf(sqrtf(ssq[b*256 + 128 + h*64 + t]), 1e-12f);
  __syncthreads();
  if (t < 8){
    int c = c0 + t;
    float rq = (1.0f/fmaxf(sqrtf(ssq[b*256 + h*64 + c]), 1e-12f))*scale[h];
    float vals[64], vmax = -1e30f;
    for (int d = 0; d < 64; d++){
      float v = red[t][d]*rq*rnk[d];
      vals[d] = v; vmax = fmaxf(vmax, v);
    }
    float* aw = out + 512 + ((size_t)(b*128 + h*64 + c))*64;
    for (int d = 0; d < 64; d++) aw[d] = vals[d];
    float se = 0.f;
    for (int d = 0; d < 64; d++){ float e = expf(vals[d]-vmax); vals[d] = e; se += e; }
    float inv = 1.0f/se;
    float* ar = ws_a + ((size_t)(b*128 + h*64 + c))*64;
    for (int d = 0; d < 64; d++) ar[d] = vals[d]*inv;
  }
}

// out = a @ v2 (block-diag per head) + per-pixel LN stats
__global__ __launch_bounds__(256,2) void k_av(const float* __restrict__ ws_a,
                                              const float* __restrict__ buf,
                                              float* __restrict__ dst,
                                              float* __restrict__ mu2,
                                              float* __restrict__ rstd2)
{
  __shared__ float a_t[64][128];
  __shared__ float v_l[128][64];
  int t = threadIdx.x;
  int pt = blockIdx.x, b = blockIdx.y;
  int p0 = pt*64;
  {
    int c = t>>1, dh = (t&1)<<5;
    const float* ap = ws_a + ((size_t)(b*128 + c))*64 + dh;
    #pragma unroll
    for (int u = 0; u < 8; u++){
      float4 v = *(const float4*)(ap + u*4);
      int d = dh + u*4;
      a_t[d+0][c] = v.x; a_t[d+1][c] = v.y; a_t[d+2][c] = v.z; a_t[d+3][c] = v.w;
    }
    const float* vp = buf + ((size_t)(b*384 + 256 + c))*HW + p0 + dh;
    #pragma unroll
    for (int u = 0; u < 8; u++)
      *(float4*)&v_l[c][dh + u*4] = *(const float4*)(vp + u*4);
  }
  __syncthreads();
  int tm = (t>>4)<<3, tp = (t&15)<<2;
  int hd = tm>>6;
  float acc[8][4] = {};
  #pragma unroll 2
  for (int d = 0; d < 64; d++){
    float4 v4 = *(const float4*)&v_l[hd*64+d][tp];
    float vv[4] = {v4.x,v4.y,v4.z,v4.w};
    #pragma unroll
    for (int i = 0; i < 8; i++){
      float av = a_t[d][tm+i];
      #pragma unroll
      for (int j = 0; j < 4; j++) acc[i][j] += av*vv[j];
    }
  }
  #pragma unroll
  for (int i = 0; i < 8; i++)
    *(float4*)(dst + ((size_t)(b*384 + tm+i))*HW + p0 + tp)
        = make_float4(acc[i][0],acc[i][1],acc[i][2],acc[i][3]);
  __syncthreads();
  float* px = &a_t[0][0];
  if (t < 128) px[t] = 0.f;
  __syncthreads();
  #pragma unroll
  for (int j = 0; j < 4; j++){
    float s = 0.f, q = 0.f;
    #pragma unroll
    for (int i = 0; i < 8; i++){ s += acc[i][j]; q += acc[i][j]*acc[i][j]; }
    atomicAdd(&px[tp+j], s);
    atomicAdd(&px[64+tp+j], q);
  }
  __syncthreads();
  if (t < 64){
    float mu  = px[t]*(1.f/128.f);
    float var = px[64+t]*(1.f/128.f) - mu*mu;
    mu2[(size_t)b*HW + p0 + t]   = mu;
    rstd2[(size_t)b*HW + p0 + t] = rsqrtf(var + 1e-5f);
  }
}

// ffn = f_out @ z (z = BUF ch 0..255); avg/max pool only (no materialization)
__global__ __launch_bounds__(256,4) void k_fout(const float* __restrict__ buf_z,
                                                const float* __restrict__ ft,
                                                float* __restrict__ avg,
                                                unsigned* __restrict__ maxk)
{
  __shared__ float z_l[64][128];
  __shared__ float osum[128];
  __shared__ unsigned okey[128];
  int t = threadIdx.x;
  int pt = blockIdx.x, b = blockIdx.y;
  int p0 = pt*128;
  int oc = (t>>4)<<3, px = (t&15)<<3;
  float acc[8][8] = {};
  for (int ks = 0; ks < 4; ks++){
    __syncthreads();
    {
      int c = t>>2, ph = (t&3)<<5;
      const float* zp = buf_z + ((size_t)(b*384 + ks*64 + c))*HW + p0 + ph;
      #pragma unroll
      for (int u = 0; u < 8; u++)
        *(float4*)&z_l[c][ph + u*4] = *(const float4*)(zp + u*4);
    }
    __syncthreads();
    #pragma unroll 2
    for (int k = 0; k < 64; k++){
      const float* fp = ft + (size_t)(ks*64 + k)*128 + oc;
      float4 f0 = *(const float4*)fp;
      float4 f1 = *(const float4*)(fp+4);
      float4 z0 = *(const float4*)&z_l[k][px];
      float4 z1 = *(const float4*)&z_l[k][px+4];
      float fv[8] = {f0.x,f0.y,f0.z,f0.w,f1.x,f1.y,f1.z,f1.w};
      float zv[8] = {z0.x,z0.y,z0.z,z0.w,z1.x,z1.y,z1.z,z1.w};
      #pragma unroll
      for (int i = 0; i < 8; i++)
        #pragma unroll
        for (int j = 0; j < 8; j++) acc[i][j] += fv[i]*zv[j];
    }
  }
  #pragma unroll
  for (int i = 0; i < 8; i++){
    float s = 0.f, mx = -1e30f;
    #pragma unroll
    for (int j = 0; j < 8; j++){ s += acc[i][j]; mx = fmaxf(mx, acc[i][j]); }
    #pragma unroll
    for (int off = 1; off < 16; off <<= 1){
      s += __shfl_xor(s, off);
      mx = fmaxf(mx, __shfl_xor(mx, off));
    }
    if ((t & 15) == 0){ osum[oc+i] = s; okey[oc+i] = f2key(mx); }
  }
  __syncthreads();
  if (t < 128){
    atomicAdd(&avg[b*128+t], osum[t]);
    atomicMax(&maxk[b*128+t], okey[t]);
  }
}

__global__ __launch_bounds__(128) void k_gate(const float* __restrict__ avg,
                                              const unsigned* __restrict__ maxk,
                                              const float* __restrict__ w1, const float* __restrict__ b1,
                                              const float* __restrict__ w2, const float* __restrict__ b2,
                                              float* __restrict__ out)
{
  __shared__ float ap[128], mp[128], h1a[8], h1m[8];
  int t = threadIdx.x, b = blockIdx.x;
  ap[t] = avg[b*128+t]*(1.0f/36864.0f);
  mp[t] = key2f(maxk[b*128+t]);
  __syncthreads();
  if (t < 8){
    float sa = b1[t], sm = b1[t];
    for (int c = 0; c < 128; c++){ float w = w1[t*128+c]; sa += w*ap[c]; sm += w*mp[c]; }
    h1a[t] = fmaxf(sa, 0.f); h1m[t] = fmaxf(sm, 0.f);
  }
  __syncthreads();
  float y = 2.0f*b2[t];
  for (int r = 0; r < 8; r++) y += w2[t*8+r]*(h1a[r]+h1m[r]);
  out[b*128+t] = 1.0f/(1.0f+expf(-y));
}

extern "C" void kernel_launch(void* const* d_in, const int* in_sizes, int n_in,
                              void* d_out, int out_size, void* d_ws, size_t ws_size,
                              hipStream_t stream)
{
  const float* x        = (const float*)d_in[0];
  const float* ln_in_w  = (const float*)d_in[1];
  const float* ln_in_b  = (const float*)d_in[2];
  const float* wq_pw    = (const float*)d_in[3];
  const float* wq_dw    = (const float*)d_in[4];
  const float* wk_pw    = (const float*)d_in[5];
  const float* wk_dw    = (const float*)d_in[6];
  const float* wv_pw    = (const float*)d_in[7];
  const float* wv_dw    = (const float*)d_in[8];
  const float* scale    = (const float*)d_in[9];
  const float* ln_out_w = (const float*)d_in[10];
  const float* ln_out_b = (const float*)d_in[11];
  const float* f1_pw    = (const float*)d_in[12];
  const float* f1_dw    = (const float*)d_in[13];
  const float* f2_pw    = (const float*)d_in[14];
  const float* f2_dw    = (const float*)d_in[15];
  const float* f_out    = (const float*)d_in[16];
  const float* g_w1     = (const float*)d_in[17];
  const float* g_b1     = (const float*)d_in[18];
  const float* g_w2     = (const float*)d_in[19];
  const float* g_b2     = (const float*)d_in[20];
  float* ws  = (float*)d_ws;
  float* out = (float*)d_out;
  float* BUF = ws + OFF_BUF1;

  k_init<<<dim3(8), dim3(256), 0, stream>>>(ws);
  k_prep<<<dim3(131), dim3(256), 0, stream>>>(wq_pw, wk_pw, wv_pw, f1_pw, f2_pw, f_out,
                                              ln_in_w, ln_in_b, ln_out_w, ln_out_b, ws);
  k_stats<<<dim3(36,4), dim3(256), 0, stream>>>(x, ws);
  // q1,k1 (LN folded) -> slots 0,1
  k_gemm<false><<<dim3(2,288,4), dim3(256), 0, stream>>>(
      x, 128, wq_pw, wk_pw, wk_pw, ln_in_w,
      ws+OFF_RS_QKV, ws+OFF_B_QKV, ws+OFF_MU1, ws+OFF_RSTD1, BUF, 0);
  // q2 = dw(q1): s0 -> s2 (+ssq); k2 = dw(k1): s1 -> s0 (+ssq)
  k_dw<false,true><<<dim3(24,128,4), dim3(256), 0, stream>>>(
      BUF, wq_dw, BUF + (size_t)256*HW, ws+OFF_SSQ, 0);
  k_dw<false,true><<<dim3(24,128,4), dim3(256), 0, stream>>>(
      BUF + (size_t)128*HW, wk_dw, BUF, ws+OFF_SSQ, 128);
  // gram partials + softmax
  k_qk<<<dim3(64,2,4), dim3(256), 0, stream>>>(BUF, ws+OFF_PART);
  k_softmax<<<dim3(8,2,4), dim3(256), 0, stream>>>(
      ws+OFF_PART, ws+OFF_SSQ, scale, ws+OFF_A, out);
  // v1 -> s1 ; v2 = dw(v1): s1 -> s2
  k_gemm<false><<<dim3(1,288,4), dim3(256), 0, stream>>>(
      x, 128, wv_pw, wv_pw, wv_pw, ln_in_w,
      ws+OFF_RS_QKV+256, ws+OFF_B_QKV+256, ws+OFF_MU1, ws+OFF_RSTD1, BUF, 128);
  k_dw<false,false><<<dim3(24,128,4), dim3(256), 0, stream>>>(
      BUF + (size_t)128*HW, wv_dw, BUF + (size_t)256*HW, nullptr, 0);
  // out = a @ v2 -> s0, + LN2 stats
  k_av<<<dim3(576,4), dim3(256), 0, stream>>>(
      ws+OFF_A, BUF, BUF, ws+OFF_MU2, ws+OFF_RSTD2);
  // FFN 1x1 (LN folded) + GELU: out(s0) -> g1(s1), g2(s2)
  k_gemm<true><<<dim3(2,288,4), dim3(256), 0, stream>>>(
      BUF, 384, f1_pw, f2_pw, f2_pw, ln_out_w,
      ws+OFF_RS_FFN, ws+OFF_B_FFN, ws+OFF_MU2, ws+OFF_RSTD2, BUF, 128);
  // z1 = gelu(dw(g1)): s1 -> s0 ; z2 = gelu(dw(g2)): s2 -> s1
  k_dw<true,false><<<dim3(24,128,4), dim3(256), 0, stream>>>(
      BUF + (size_t)128*HW, f1_dw, BUF, nullptr, 0);
  k_dw<true,false><<<dim3(24,128,4), dim3(256), 0, stream>>>(
      BUF + (size_t)256*HW, f2_dw, BUF + (size_t)128*HW, nullptr, 0);
  // f_out GEMM + pools
  k_fout<<<dim3(288,4), dim3(256), 0, stream>>>(
      BUF, ws+OFF_FT, ws+OFF_AVG, (unsigned*)(ws+OFF_MAXK));
  k_gate<<<dim3(4), dim3(128), 0, stream>>>(
      ws+OFF_AVG, (const unsigned*)(ws+OFF_MAXK), g_w1, g_b1, g_w2, g_b2, out);

  (void)in_sizes; (void)n_in; (void)out_size; (void)ws_size;
}

// Round 3
// 832.095 us; speedup vs baseline: 3.1909x; 1.1876x over previous
//
#include <hip/hip_runtime.h>
#include <math.h>

#define HW    36864
#define IMG   192

// ---- ws layout (float offsets) ----
#define OFF_RS_QKV   0          // 384
#define OFF_B_QKV    384        // 384
#define OFF_RS_FFN   768        // 256
#define OFF_B_FFN    1024       // 256
#define OFF_SSQ      1280       // 1024 [zeroed]
#define OFF_AVG      2304       // 512  [zeroed]
#define OFF_MAXK     2816       // 512  [zeroed]
#define OFF_A        3328       // 32768 softmax probs
#define OFF_MU1      36096      // 147456
#define OFF_RSTD1    183552     // 147456
#define OFF_MU2      331008     // 147456
#define OFF_RSTD2    478464     // 147456
#define OFF_PART     625920     // 8*64*4096 = 2097152
#define OFF_AQH      2723072    // 384x128 bf16 hi  (24576 floats)
#define OFF_AQL      2747648    // 24576
#define OFF_AFH      2772224    // 256x128 bf16 hi  (16384)
#define OFF_AFL      2788608    // 16384
#define OFF_AOH      2804992    // 128x256 bf16 hi  (16384)
#define OFF_AOL      2821376    // 16384
#define OFF_BUF1     2837760    // 4*384*36864 = 56623104 -> end 59460864 (237.8 MB)

typedef __attribute__((ext_vector_type(8))) short short8v;
typedef __attribute__((ext_vector_type(4))) float floatx4;

__device__ __forceinline__ unsigned f2key(float f){
  unsigned b = __float_as_uint(f);
  return (b & 0x80000000u) ? ~b : (b | 0x80000000u);
}
__device__ __forceinline__ float key2f(unsigned k){
  return __uint_as_float((k & 0x80000000u) ? (k & 0x7fffffffu) : ~k);
}
__device__ __forceinline__ float gelu_f(float v){
  return 0.5f*v*(1.0f + erff(v*0.70710678118654752f));
}
__device__ __forceinline__ unsigned short bf16rn(float v){
  unsigned u = __float_as_uint(v);
  return (unsigned short)((u + 0x7FFFu + ((u>>16)&1u)) >> 16);
}
__device__ __forceinline__ float bf2f(unsigned short h){
  return __uint_as_float(((unsigned)h)<<16);
}
// swizzled LDS offset (ushort units): row pitch 128, 16B-block XOR swizzle
__device__ __forceinline__ int bofs(int p, int k){
  return (p<<7) + ((((k>>3) ^ (p&15) ^ ((p>>4)&7)))<<3) + (k&7);
}

__global__ __launch_bounds__(256) void k_init(float* ws){
  int t = blockIdx.x*256 + threadIdx.x;
  if (t < 2048) ws[OFF_SSQ + t] = 0.0f;   // ssq + avg + maxkey
}

// LN fold constants + split-bf16 weight tables
__global__ void k_prep(const float* wq, const float* wk, const float* wv,
                       const float* f1, const float* f2, const float* fo,
                       const float* liw, const float* lib,
                       const float* low, const float* lob, float* ws){
  int t = blockIdx.x*256 + threadIdx.x;
  if (t < 384){
    const float* W = (t < 128) ? wq : (t < 256) ? wk : wv;
    int r = t & 127;
    float rs = 0.f, bs = 0.f;
    for (int c = 0; c < 128; c++){ float w = W[r*128+c]; rs += w*liw[c]; bs += w*lib[c]; }
    ws[OFF_RS_QKV+t] = rs; ws[OFF_B_QKV+t] = bs;
  } else if (t < 640){
    int m = t - 384;
    const float* W = (m < 128) ? f1 : f2;
    int r = m & 127;
    float rs = 0.f, bs = 0.f;
    for (int c = 0; c < 128; c++){ float w = W[r*128+c]; rs += w*low[c]; bs += w*lob[c]; }
    ws[OFF_RS_FFN+m] = rs; ws[OFF_B_FFN+m] = bs;
  }
  int e = t - 640;
  if (e < 0) return;
  unsigned short* aqh = (unsigned short*)(ws + OFF_AQH);
  unsigned short* aql = (unsigned short*)(ws + OFF_AQL);
  unsigned short* afh = (unsigned short*)(ws + OFF_AFH);
  unsigned short* afl = (unsigned short*)(ws + OFF_AFL);
  unsigned short* aoh = (unsigned short*)(ws + OFF_AOH);
  unsigned short* aol = (unsigned short*)(ws + OFF_AOL);
  if (e < 49152){
    int m = e>>7, k = e&127;
    const float* W = (m < 128) ? wq : (m < 256) ? wk : wv;
    float v = W[(m&127)*128 + k]*liw[k];
    unsigned short h = bf16rn(v);
    aqh[e] = h; aql[e] = bf16rn(v - bf2f(h));
  } else if (e < 81920){
    int e2 = e - 49152;
    int m = e2>>7, k = e2&127;
    const float* W = (m < 128) ? f1 : f2;
    float v = W[(m&127)*128 + k]*low[k];
    unsigned short h = bf16rn(v);
    afh[e2] = h; afl[e2] = bf16rn(v - bf2f(h));
  } else if (e < 114688){
    int e2 = e - 81920;
    float v = fo[e2];
    unsigned short h = bf16rn(v);
    aoh[e2] = h; aol[e2] = bf16rn(v - bf2f(h));
  }
}

// per-pixel channel mean / rstd of x (4 px per thread, float4)
__global__ __launch_bounds__(256) void k_stats(const float* __restrict__ x, float* __restrict__ ws){
  int t = threadIdx.x, b = blockIdx.y;
  int p0 = blockIdx.x*1024 + t*4;
  const float* xp = x + (size_t)b*128*HW + p0;
  float s[4] = {}, q[4] = {};
  #pragma unroll 4
  for (int c = 0; c < 128; c++){
    float4 v = *(const float4*)(xp + (size_t)c*HW);
    float vv[4] = {v.x,v.y,v.z,v.w};
    #pragma unroll
    for (int j = 0; j < 4; j++){ s[j] += vv[j]; q[j] += vv[j]*vv[j]; }
  }
  float mu[4], rs[4];
  #pragma unroll
  for (int j = 0; j < 4; j++){
    mu[j] = s[j]*(1.f/128.f);
    rs[j] = rsqrtf(q[j]*(1.f/128.f) - mu[j]*mu[j] + 1e-5f);
  }
  size_t g = (size_t)b*HW + p0;
  *(float4*)&ws[OFF_MU1 + g]   = make_float4(mu[0],mu[1],mu[2],mu[3]);
  *(float4*)&ws[OFF_RSTD1 + g] = make_float4(rs[0],rs[1],rs[2],rs[3]);
}

// split-bf16 MFMA GEMM: dst[m][p] = LN-epilogue( sum_k A[m][k]*src[k][p] )
// A pre-split to bf16 hi/lo tables (LN weight folded); src split on the fly.
template<bool GELU>
__global__ __launch_bounds__(256,2) void k_gemm_mfma(
    const float* __restrict__ src, int src_bstride,
    const unsigned short* __restrict__ Ahi, const unsigned short* __restrict__ Alo,
    const float* __restrict__ rowsum, const float* __restrict__ bias,
    const float* __restrict__ mu, const float* __restrict__ rstd,
    float* __restrict__ dst, int dst_coff)
{
  __shared__ unsigned short BsH[16384];
  __shared__ unsigned short BsL[16384];
  int t = threadIdx.x;
  int m0 = blockIdx.x*128, p0 = blockIdx.y*128, b = blockIdx.z;
  // ---- stage B tile (128k x 128p) as swizzled bf16 hi/lo ----
  {
    int px0 = (t&31)*4;
    int kb0 = t>>5;
    #pragma unroll
    for (int ki = 0; ki < 2; ki++){
      int kb = kb0 + ki*8;
      float vals[8][4];
      #pragma unroll
      for (int e = 0; e < 8; e++){
        const float* sp = src + ((size_t)(b*src_bstride + kb*8 + e))*HW + p0 + px0;
        float4 v = *(const float4*)sp;
        vals[e][0]=v.x; vals[e][1]=v.y; vals[e][2]=v.z; vals[e][3]=v.w;
      }
      #pragma unroll
      for (int j = 0; j < 4; j++){
        short8v hv, lv;
        #pragma unroll
        for (int e = 0; e < 8; e++){
          float v = vals[e][j];
          unsigned short h = bf16rn(v);
          unsigned short l = bf16rn(v - bf2f(h));
          hv[e] = (short)h; lv[e] = (short)l;
        }
        int o = bofs(px0+j, kb*8);
        *(short8v*)&BsH[o] = hv;
        *(short8v*)&BsL[o] = lv;
      }
    }
  }
  __syncthreads();
  int lane = t & 63, wv = t>>6;
  int wm = (wv>>1)*64, wn = (wv&1)*64;
  int colg = lane&15, kg = lane>>4;
  floatx4 acc[4][4];
  #pragma unroll
  for (int i = 0; i < 4; i++)
    #pragma unroll
    for (int j = 0; j < 4; j++) acc[i][j] = (floatx4){0.f,0.f,0.f,0.f};

  #pragma unroll
  for (int kt = 0; kt < 4; kt++){
    int kb = kt*32 + kg*8;
    short8v ah[4], al[4], bh[4], bl[4];
    #pragma unroll
    for (int f = 0; f < 4; f++){
      size_t arow = (size_t)(m0 + wm + f*16 + colg)*128 + kb;
      ah[f] = *(const short8v*)(Ahi + arow);
      al[f] = *(const short8v*)(Alo + arow);
      int o = bofs(wn + f*16 + colg, kb);
      bh[f] = *(const short8v*)&BsH[o];
      bl[f] = *(const short8v*)&BsL[o];
    }
    #pragma unroll
    for (int i = 0; i < 4; i++)
      #pragma unroll
      for (int j = 0; j < 4; j++){
        acc[i][j] = __builtin_amdgcn_mfma_f32_16x16x32_bf16(al[i], bh[j], acc[i][j], 0,0,0);
        acc[i][j] = __builtin_amdgcn_mfma_f32_16x16x32_bf16(ah[i], bl[j], acc[i][j], 0,0,0);
        acc[i][j] = __builtin_amdgcn_mfma_f32_16x16x32_bf16(ah[i], bh[j], acc[i][j], 0,0,0);
      }
  }

  int rowg = kg*4;
  const float* mub = mu   + (size_t)b*HW + p0;
  const float* rsb = rstd + (size_t)b*HW + p0;
  #pragma unroll
  for (int j = 0; j < 4; j++){
    int pc = wn + j*16 + colg;
    float muv = mub[pc], rsv = rsb[pc];
    #pragma unroll
    for (int i = 0; i < 4; i++){
      int mbase = m0 + wm + i*16 + rowg;
      float4 rs4 = *(const float4*)&rowsum[mbase];
      float4 bi4 = *(const float4*)&bias[mbase];
      float rsa[4] = {rs4.x,rs4.y,rs4.z,rs4.w};
      float bia[4] = {bi4.x,bi4.y,bi4.z,bi4.w};
      #pragma unroll
      for (int e = 0; e < 4; e++){
        float v = rsv*(acc[i][j][e] - muv*rsa[e]) + bia[e];
        if (GELU) v = gelu_f(v);
        dst[((size_t)(b*384 + dst_coff + mbase + e))*HW + p0 + pc] = v;
      }
    }
  }
}

// streaming depthwise 3x3 (pad 1)
template<bool GELU, bool SSQ>
__global__ __launch_bounds__(256) void k_dw(const float* __restrict__ src,
                                            const float* __restrict__ wdw,
                                            float* __restrict__ dst,
                                            float* __restrict__ ssq, int ssq_off){
  __shared__ float rows[10][194];
  __shared__ float wred[4];
  int t = threadIdx.x;
  int band = blockIdx.x, c = blockIdx.y, b = blockIdx.z;
  const float* sp = src + ((size_t)(b*384 + c))*HW;
  float w[9];
  #pragma unroll
  for (int j = 0; j < 9; j++) w[j] = wdw[c*9 + j];
  int r0 = band*8;
  for (int e = t; e < 1920; e += 256){
    int r = e/192, cc = e - r*192;
    int gr = r0 + r - 1;
    rows[r][cc+1] = (gr >= 0 && gr < IMG) ? sp[gr*IMG + cc] : 0.f;
  }
  if (t < 20) rows[t>>1][(t&1)*193] = 0.f;
  __syncthreads();
  float s2 = 0.f;
  float* dp = dst + ((size_t)(b*384 + c))*HW + r0*IMG;
  #pragma unroll
  for (int i = 0; i < 6; i++){
    int px = i*256 + t;
    int r = px/192, cc = px - r*192;
    float v = 0.f;
    #pragma unroll
    for (int dy = 0; dy < 3; dy++)
      #pragma unroll
      for (int dx = 0; dx < 3; dx++)
        v += rows[r+dy][cc+dx] * w[dy*3+dx];
    if (GELU) v = gelu_f(v);
    dp[px] = v;
    if (SSQ) s2 += v*v;
  }
  if (SSQ){
    #pragma unroll
    for (int off = 32; off; off >>= 1) s2 += __shfl_xor(s2, off);
    if ((t & 63) == 0) wred[t>>6] = s2;
    __syncthreads();
    if (t == 0) atomicAdd(&ssq[b*256 + ssq_off + c], wred[0]+wred[1]+wred[2]+wred[3]);
  }
}

// split-K 64x64 gram (fp32): part = sum over 576 px of q2[c][p]*k2[d][p]
__global__ __launch_bounds__(256,4) void k_qk(const float* __restrict__ buf,
                                              float* __restrict__ part){
  __shared__ float qs[64][68];
  __shared__ float ks[64][68];
  int t = threadIdx.x;
  int chunk = blockIdx.x, h = blockIdx.y, b = blockIdx.z;
  int tc = (t>>4)<<2, td = (t&15)<<2;
  int c = t>>2, pq = (t&3)<<4;
  const float* qp = buf + ((size_t)(b*384 + 256 + h*64 + c))*HW + chunk*576 + pq;
  const float* kp = buf + ((size_t)(b*384 +       h*64 + c))*HW + chunk*576 + pq;
  float acc[4][4] = {};
  for (int st = 0; st < 9; st++){
    __syncthreads();
    #pragma unroll
    for (int u = 0; u < 4; u++){
      float4 qv = *(const float4*)(qp + st*64 + u*4);
      float4 kv = *(const float4*)(kp + st*64 + u*4);
      int p = pq + u*4;
      qs[p+0][c] = qv.x; qs[p+1][c] = qv.y; qs[p+2][c] = qv.z; qs[p+3][c] = qv.w;
      ks[p+0][c] = kv.x; ks[p+1][c] = kv.y; ks[p+2][c] = kv.z; ks[p+3][c] = kv.w;
    }
    __syncthreads();
    #pragma unroll 4
    for (int p = 0; p < 64; p++){
      float4 q4 = *(const float4*)&qs[p][tc];
      float4 k4 = *(const float4*)&ks[p][td];
      float qa[4] = {q4.x,q4.y,q4.z,q4.w};
      float ka[4] = {k4.x,k4.y,k4.z,k4.w};
      #pragma unroll
      for (int i = 0; i < 4; i++)
        #pragma unroll
        for (int j = 0; j < 4; j++) acc[i][j] += qa[i]*ka[j];
    }
  }
  float* pp = part + ((size_t)((b*2+h)*64 + chunk))*4096;
  #pragma unroll
  for (int i = 0; i < 4; i++)
    *(float4*)&pp[(tc+i)*64 + td] = make_float4(acc[i][0],acc[i][1],acc[i][2],acc[i][3]);
}

__global__ __launch_bounds__(256) void k_softmax(const float* __restrict__ part,
                                                 const float* __restrict__ ssq,
                                                 const float* __restrict__ scale,
                                                 float* __restrict__ ws_a,
                                                 float* __restrict__ out)
{
  __shared__ float red[8][64];
  __shared__ float rnk[64];
  int t = threadIdx.x;
  int c0 = blockIdx.x*8, h = blockIdx.y, b = blockIdx.z;
  int bh = b*2 + h;
  const float* pp = part + (size_t)bh*64*4096;
  for (int e = t; e < 512; e += 256){
    int c = e>>6, d = e&63;
    float s = 0.f;
    for (int ch = 0; ch < 64; ch++) s += pp[(size_t)ch*4096 + (c0+c)*64 + d];
    red[c][d] = s;
  }
  if (t < 64) rnk[t] = 1.0f/fmaxf(sqrtf(ssq[b*256 + 128 + h*64 + t]), 1e-12f);
  __syncthreads();
  if (t < 8){
    int c = c0 + t;
    float rq = (1.0f/fmaxf(sqrtf(ssq[b*256 + h*64 + c]), 1e-12f))*scale[h];
    float vals[64], vmax = -1e30f;
    for (int d = 0; d < 64; d++){
      float v = red[t][d]*rq*rnk[d];
      vals[d] = v; vmax = fmaxf(vmax, v);
    }
    float* aw = out + 512 + ((size_t)(b*128 + h*64 + c))*64;
    for (int d = 0; d < 64; d++) aw[d] = vals[d];
    float se = 0.f;
    for (int d = 0; d < 64; d++){ float e = expf(vals[d]-vmax); vals[d] = e; se += e; }
    float inv = 1.0f/se;
    float* ar = ws_a + ((size_t)(b*128 + h*64 + c))*64;
    for (int d = 0; d < 64; d++) ar[d] = vals[d]*inv;
  }
}

// out = a @ v2 (block-diag per head) + per-pixel LN stats
__global__ __launch_bounds__(256,2) void k_av(const float* __restrict__ ws_a,
                                              const float* __restrict__ buf,
                                              float* __restrict__ dst,
                                              float* __restrict__ mu2,
                                              float* __restrict__ rstd2)
{
  __shared__ float a_t[64][128];
  __shared__ float v_l[128][64];
  int t = threadIdx.x;
  int pt = blockIdx.x, b = blockIdx.y;
  int p0 = pt*64;
  {
    int c = t>>1, dh = (t&1)<<5;
    const float* ap = ws_a + ((size_t)(b*128 + c))*64 + dh;
    #pragma unroll
    for (int u = 0; u < 8; u++){
      float4 v = *(const float4*)(ap + u*4);
      int d = dh + u*4;
      a_t[d+0][c] = v.x; a_t[d+1][c] = v.y; a_t[d+2][c] = v.z; a_t[d+3][c] = v.w;
    }
    const float* vp = buf + ((size_t)(b*384 + 256 + c))*HW + p0 + dh;
    #pragma unroll
    for (int u = 0; u < 8; u++)
      *(float4*)&v_l[c][dh + u*4] = *(const float4*)(vp + u*4);
  }
  __syncthreads();
  int tm = (t>>4)<<3, tp = (t&15)<<2;
  int hd = tm>>6;
  float acc[8][4] = {};
  #pragma unroll 2
  for (int d = 0; d < 64; d++){
    float4 v4 = *(const float4*)&v_l[hd*64+d][tp];
    float vv[4] = {v4.x,v4.y,v4.z,v4.w};
    #pragma unroll
    for (int i = 0; i < 8; i++){
      float av = a_t[d][tm+i];
      #pragma unroll
      for (int j = 0; j < 4; j++) acc[i][j] += av*vv[j];
    }
  }
  #pragma unroll
  for (int i = 0; i < 8; i++)
    *(float4*)(dst + ((size_t)(b*384 + tm+i))*HW + p0 + tp)
        = make_float4(acc[i][0],acc[i][1],acc[i][2],acc[i][3]);
  __syncthreads();
  float* px = &a_t[0][0];
  if (t < 128) px[t] = 0.f;
  __syncthreads();
  #pragma unroll
  for (int j = 0; j < 4; j++){
    float s = 0.f, q = 0.f;
    #pragma unroll
    for (int i = 0; i < 8; i++){ s += acc[i][j]; q += acc[i][j]*acc[i][j]; }
    atomicAdd(&px[tp+j], s);
    atomicAdd(&px[64+tp+j], q);
  }
  __syncthreads();
  if (t < 64){
    float mu  = px[t]*(1.f/128.f);
    float var = px[64+t]*(1.f/128.f) - mu*mu;
    mu2[(size_t)b*HW + p0 + t]   = mu;
    rstd2[(size_t)b*HW + p0 + t] = rsqrtf(var + 1e-5f);
  }
}

// f_out GEMM via split-bf16 MFMA; epilogue = avg/max pool only
__global__ __launch_bounds__(256,2) void k_fout_mfma(
    const float* __restrict__ bufz,
    const unsigned short* __restrict__ Ahi, const unsigned short* __restrict__ Alo,
    float* __restrict__ avg, unsigned* __restrict__ maxk)
{
  __shared__ unsigned short BsH[16384];
  __shared__ unsigned short BsL[16384];
  __shared__ float osum[128];
  __shared__ unsigned okey[128];
  int t = threadIdx.x;
  int p0 = blockIdx.x*128, b = blockIdx.y;
  if (t < 128){ osum[t] = 0.f; okey[t] = 0u; }
  int lane = t & 63, wv = t>>6;
  int wm = (wv>>1)*64, wn = (wv&1)*64;
  int colg = lane&15, kg = lane>>4;
  floatx4 acc[4][4];
  #pragma unroll
  for (int i = 0; i < 4; i++)
    #pragma unroll
    for (int j = 0; j < 4; j++) acc[i][j] = (floatx4){0.f,0.f,0.f,0.f};

  for (int half = 0; half < 2; half++){
    __syncthreads();
    {
      int px0 = (t&31)*4;
      int kb0 = t>>5;
      #pragma unroll
      for (int ki = 0; ki < 2; ki++){
        int kb = kb0 + ki*8;
        float vals[8][4];
        #pragma unroll
        for (int e = 0; e < 8; e++){
          const float* sp = bufz + ((size_t)(b*384 + half*128 + kb*8 + e))*HW + p0 + px0;
          float4 v = *(const float4*)sp;
          vals[e][0]=v.x; vals[e][1]=v.y; vals[e][2]=v.z; vals[e][3]=v.w;
        }
        #pragma unroll
        for (int j = 0; j < 4; j++){
          short8v hv, lv;
          #pragma unroll
          for (int e = 0; e < 8; e++){
            float v = vals[e][j];
            unsigned short h = bf16rn(v);
            unsigned short l = bf16rn(v - bf2f(h));
            hv[e] = (short)h; lv[e] = (short)l;
          }
          int o = bofs(px0+j, kb*8);
          *(short8v*)&BsH[o] = hv;
          *(short8v*)&BsL[o] = lv;
        }
      }
    }
    __syncthreads();
    #pragma unroll
    for (int kt = 0; kt < 4; kt++){
      int kb = kt*32 + kg*8;
      short8v ah[4], al[4], bh[4], bl[4];
      #pragma unroll
      for (int f = 0; f < 4; f++){
        size_t arow = (size_t)(wm + f*16 + colg)*256 + half*128 + kb;
        ah[f] = *(const short8v*)(Ahi + arow);
        al[f] = *(const short8v*)(Alo + arow);
        int o = bofs(wn + f*16 + colg, kb);
        bh[f] = *(const short8v*)&BsH[o];
        bl[f] = *(const short8v*)&BsL[o];
      }
      #pragma unroll
      for (int i = 0; i < 4; i++)
        #pragma unroll
        for (int j = 0; j < 4; j++){
          acc[i][j] = __builtin_amdgcn_mfma_f32_16x16x32_bf16(al[i], bh[j], acc[i][j], 0,0,0);
          acc[i][j] = __builtin_amdgcn_mfma_f32_16x16x32_bf16(ah[i], bl[j], acc[i][j], 0,0,0);
          acc[i][j] = __builtin_amdgcn_mfma_f32_16x16x32_bf16(ah[i], bh[j], acc[i][j], 0,0,0);
        }
    }
  }
  int rowg = kg*4;
  #pragma unroll
  for (int i = 0; i < 4; i++){
    #pragma unroll
    for (int e = 0; e < 4; e++){
      float s = 0.f, mx = -1e30f;
      #pragma unroll
      for (int j = 0; j < 4; j++){ float v = acc[i][j][e]; s += v; mx = fmaxf(mx, v); }
      #pragma unroll
      for (int off = 1; off < 16; off <<= 1){
        s += __shfl_xor(s, off);
        mx = fmaxf(mx, __shfl_xor(mx, off));
      }
      if (colg == 0){
        int oc = wm + i*16 + rowg + e;
        atomicAdd(&osum[oc], s);
        atomicMax(&okey[oc], f2key(mx));
      }
    }
  }
  __syncthreads();
  if (t < 128){
    atomicAdd(&avg[b*128+t], osum[t]);
    atomicMax(&maxk[b*128+t], okey[t]);
  }
}

__global__ __launch_bounds__(128) void k_gate(const float* __restrict__ avg,
                                              const unsigned* __restrict__ maxk,
                                              const float* __restrict__ w1, const float* __restrict__ b1,
                                              const float* __restrict__ w2, const float* __restrict__ b2,
                                              float* __restrict__ out)
{
  __shared__ float ap[128], mp[128], h1a[8], h1m[8];
  int t = threadIdx.x, b = blockIdx.x;
  ap[t] = avg[b*128+t]*(1.0f/36864.0f);
  mp[t] = key2f(maxk[b*128+t]);
  __syncthreads();
  if (t < 8){
    float sa = b1[t], sm = b1[t];
    for (int c = 0; c < 128; c++){ float w = w1[t*128+c]; sa += w*ap[c]; sm += w*mp[c]; }
    h1a[t] = fmaxf(sa, 0.f); h1m[t] = fmaxf(sm, 0.f);
  }
  __syncthreads();
  float y = 2.0f*b2[t];
  for (int r = 0; r < 8; r++) y += w2[t*8+r]*(h1a[r]+h1m[r]);
  out[b*128+t] = 1.0f/(1.0f+expf(-y));
}

extern "C" void kernel_launch(void* const* d_in, const int* in_sizes, int n_in,
                              void* d_out, int out_size, void* d_ws, size_t ws_size,
                              hipStream_t stream)
{
  const float* x        = (const float*)d_in[0];
  const float* ln_in_w  = (const float*)d_in[1];
  const float* ln_in_b  = (const float*)d_in[2];
  const float* wq_pw    = (const float*)d_in[3];
  const float* wq_dw    = (const float*)d_in[4];
  const float* wk_pw    = (const float*)d_in[5];
  const float* wk_dw    = (const float*)d_in[6];
  const float* wv_pw    = (const float*)d_in[7];
  const float* wv_dw    = (const float*)d_in[8];
  const float* scale    = (const float*)d_in[9];
  const float* ln_out_w = (const float*)d_in[10];
  const float* ln_out_b = (const float*)d_in[11];
  const float* f1_pw    = (const float*)d_in[12];
  const float* f1_dw    = (const float*)d_in[13];
  const float* f2_pw    = (const float*)d_in[14];
  const float* f2_dw    = (const float*)d_in[15];
  const float* f_out    = (const float*)d_in[16];
  const float* g_w1     = (const float*)d_in[17];
  const float* g_b1     = (const float*)d_in[18];
  const float* g_w2     = (const float*)d_in[19];
  const float* g_b2     = (const float*)d_in[20];
  float* ws  = (float*)d_ws;
  float* out = (float*)d_out;
  float* BUF = ws + OFF_BUF1;
  const unsigned short* aqh = (const unsigned short*)(ws + OFF_AQH);
  const unsigned short* aql = (const unsigned short*)(ws + OFF_AQL);
  const unsigned short* afh = (const unsigned short*)(ws + OFF_AFH);
  const unsigned short* afl = (const unsigned short*)(ws + OFF_AFL);
  const unsigned short* aoh = (const unsigned short*)(ws + OFF_AOH);
  const unsigned short* aol = (const unsigned short*)(ws + OFF_AOL);

  k_init<<<dim3(8), dim3(256), 0, stream>>>(ws);
  k_prep<<<dim3(451), dim3(256), 0, stream>>>(wq_pw, wk_pw, wv_pw, f1_pw, f2_pw, f_out,
                                              ln_in_w, ln_in_b, ln_out_w, ln_out_b, ws);
  k_stats<<<dim3(36,4), dim3(256), 0, stream>>>(x, ws);
  // q1,k1 (LN folded, MFMA) -> slots 0,1
  k_gemm_mfma<false><<<dim3(2,288,4), dim3(256), 0, stream>>>(
      x, 128, aqh, aql, ws+OFF_RS_QKV, ws+OFF_B_QKV,
      ws+OFF_MU1, ws+OFF_RSTD1, BUF, 0);
  // q2 = dw(q1): s0 -> s2 (+ssq); k2 = dw(k1): s1 -> s0 (+ssq)
  k_dw<false,true><<<dim3(24,128,4), dim3(256), 0, stream>>>(
      BUF, wq_dw, BUF + (size_t)256*HW, ws+OFF_SSQ, 0);
  k_dw<false,true><<<dim3(24,128,4), dim3(256), 0, stream>>>(
      BUF + (size_t)128*HW, wk_dw, BUF, ws+OFF_SSQ, 128);
  // gram partials + softmax
  k_qk<<<dim3(64,2,4), dim3(256), 0, stream>>>(BUF, ws+OFF_PART);
  k_softmax<<<dim3(8,2,4), dim3(256), 0, stream>>>(
      ws+OFF_PART, ws+OFF_SSQ, scale, ws+OFF_A, out);
  // v1 -> s1 (MFMA); v2 = dw(v1): s1 -> s2
  k_gemm_mfma<false><<<dim3(1,288,4), dim3(256), 0, stream>>>(
      x, 128, aqh + 256*128, aql + 256*128, ws+OFF_RS_QKV+256, ws+OFF_B_QKV+256,
      ws+OFF_MU1, ws+OFF_RSTD1, BUF, 128);
  k_dw<false,false><<<dim3(24,128,4), dim3(256), 0, stream>>>(
      BUF + (size_t)128*HW, wv_dw, BUF + (size_t)256*HW, nullptr, 0);
  // out = a @ v2 -> s0, + LN2 stats
  k_av<<<dim3(576,4), dim3(256), 0, stream>>>(
      ws+OFF_A, BUF, BUF, ws+OFF_MU2, ws+OFF_RSTD2);
  // FFN 1x1 (LN folded, MFMA) + GELU: out(s0) -> g1(s1), g2(s2)
  k_gemm_mfma<true><<<dim3(2,288,4), dim3(256), 0, stream>>>(
      BUF, 384, afh, afl, ws+OFF_RS_FFN, ws+OFF_B_FFN,
      ws+OFF_MU2, ws+OFF_RSTD2, BUF, 128);
  // z1 = gelu(dw(g1)): s1 -> s0 ; z2 = gelu(dw(g2)): s2 -> s1
  k_dw<true,false><<<dim3(24,128,4), dim3(256), 0, stream>>>(
      BUF + (size_t)128*HW, f1_dw, BUF, nullptr, 0);
  k_dw<true,false><<<dim3(24,128,4), dim3(256), 0, stream>>>(
      BUF + (size_t)256*HW, f2_dw, BUF + (size_t)128*HW, nullptr, 0);
  // f_out GEMM (MFMA) + pools
  k_fout_mfma<<<dim3(288,4), dim3(256), 0, stream>>>(
      BUF, aoh, aol, ws+OFF_AVG, (unsigned*)(ws+OFF_MAXK));
  k_gate<<<dim3(4), dim3(128), 0, stream>>>(
      ws+OFF_AVG, (const unsigned*)(ws+OFF_MAXK), g_w1, g_b1, g_w2, g_b2, out);

  (void)in_sizes; (void)n_in; (void)out_size; (void)ws_size;
}

// Round 4
// 755.566 us; speedup vs baseline: 3.5141x; 1.1013x over previous
//
#include <hip/hip_runtime.h>
#include <math.h>

#define HW    36864
#define IMG   192

// ---- ws layout (float offsets) ----
#define OFF_RS_QKV   0          // 384
#define OFF_B_QKV    384        // 384
#define OFF_RS_FFN   768        // 256
#define OFF_B_FFN    1024       // 256
#define OFF_SSQ      1280       // 1024 [zeroed]
#define OFF_AVG      2304       // 512  [zeroed]
#define OFF_MAXK     2816       // 512  [zeroed]
#define OFF_A        3328       // 32768 softmax probs
#define OFF_MU1      36096      // 147456
#define OFF_RSTD1    183552     // 147456
#define OFF_MU2      331008     // 147456
#define OFF_RSTD2    478464     // 147456
#define OFF_PART     625920     // 8*64*4096 = 2097152
#define OFF_AQH      2723072    // 384x128 bf16 hi  (24576 floats)
#define OFF_AQL      2747648    // 24576
#define OFF_AFH      2772224    // 256x128 bf16 hi  (16384)
#define OFF_AFL      2788608    // 16384
#define OFF_AOH      2804992    // 128x256 bf16 hi  (16384)
#define OFF_AOL      2821376    // 16384
#define OFF_BUF1     2837760    // 4*384*36864 = 56623104 -> end 59460864 (237.8 MB)

typedef __attribute__((ext_vector_type(8))) short short8v;
typedef __attribute__((ext_vector_type(4))) float floatx4;

__device__ __forceinline__ unsigned f2key(float f){
  unsigned b = __float_as_uint(f);
  return (b & 0x80000000u) ? ~b : (b | 0x80000000u);
}
__device__ __forceinline__ float key2f(unsigned k){
  return __uint_as_float((k & 0x80000000u) ? (k & 0x7fffffffu) : ~k);
}
__device__ __forceinline__ float gelu_f(float v){
  return 0.5f*v*(1.0f + erff(v*0.70710678118654752f));
}
__device__ __forceinline__ unsigned short bf16rn(float v){
  unsigned u = __float_as_uint(v);
  return (unsigned short)((u + 0x7FFFu + ((u>>16)&1u)) >> 16);
}
__device__ __forceinline__ float bf2f(unsigned short h){
  return __uint_as_float(((unsigned)h)<<16);
}

__global__ __launch_bounds__(256) void k_init(float* ws){
  int t = blockIdx.x*256 + threadIdx.x;
  if (t < 2048) ws[OFF_SSQ + t] = 0.0f;   // ssq + avg + maxkey
}

// LN fold constants + split-bf16 weight tables
__global__ void k_prep(const float* wq, const float* wk, const float* wv,
                       const float* f1, const float* f2, const float* fo,
                       const float* liw, const float* lib,
                       const float* low, const float* lob, float* ws){
  int t = blockIdx.x*256 + threadIdx.x;
  if (t < 384){
    const float* W = (t < 128) ? wq : (t < 256) ? wk : wv;
    int r = t & 127;
    float rs = 0.f, bs = 0.f;
    for (int c = 0; c < 128; c++){ float w = W[r*128+c]; rs += w*liw[c]; bs += w*lib[c]; }
    ws[OFF_RS_QKV+t] = rs; ws[OFF_B_QKV+t] = bs;
  } else if (t < 640){
    int m = t - 384;
    const float* W = (m < 128) ? f1 : f2;
    int r = m & 127;
    float rs = 0.f, bs = 0.f;
    for (int c = 0; c < 128; c++){ float w = W[r*128+c]; rs += w*low[c]; bs += w*lob[c]; }
    ws[OFF_RS_FFN+m] = rs; ws[OFF_B_FFN+m] = bs;
  }
  int e = t - 640;
  if (e < 0) return;
  unsigned short* aqh = (unsigned short*)(ws + OFF_AQH);
  unsigned short* aql = (unsigned short*)(ws + OFF_AQL);
  unsigned short* afh = (unsigned short*)(ws + OFF_AFH);
  unsigned short* afl = (unsigned short*)(ws + OFF_AFL);
  unsigned short* aoh = (unsigned short*)(ws + OFF_AOH);
  unsigned short* aol = (unsigned short*)(ws + OFF_AOL);
  if (e < 49152){
    int m = e>>7, k = e&127;
    const float* W = (m < 128) ? wq : (m < 256) ? wk : wv;
    float v = W[(m&127)*128 + k]*liw[k];
    unsigned short h = bf16rn(v);
    aqh[e] = h; aql[e] = bf16rn(v - bf2f(h));
  } else if (e < 81920){
    int e2 = e - 49152;
    int m = e2>>7, k = e2&127;
    const float* W = (m < 128) ? f1 : f2;
    float v = W[(m&127)*128 + k]*low[k];
    unsigned short h = bf16rn(v);
    afh[e2] = h; afl[e2] = bf16rn(v - bf2f(h));
  } else if (e < 114688){
    int e2 = e - 81920;
    float v = fo[e2];
    unsigned short h = bf16rn(v);
    aoh[e2] = h; aol[e2] = bf16rn(v - bf2f(h));
  }
}

// per-pixel channel mean / rstd of x (4 px per thread, float4)
__global__ __launch_bounds__(256) void k_stats(const float* __restrict__ x, float* __restrict__ ws){
  int t = threadIdx.x, b = blockIdx.y;
  int p0 = blockIdx.x*1024 + t*4;
  const float* xp = x + (size_t)b*128*HW + p0;
  float s[4] = {}, q[4] = {};
  #pragma unroll 4
  for (int c = 0; c < 128; c++){
    float4 v = *(const float4*)(xp + (size_t)c*HW);
    float vv[4] = {v.x,v.y,v.z,v.w};
    #pragma unroll
    for (int j = 0; j < 4; j++){ s[j] += vv[j]; q[j] += vv[j]*vv[j]; }
  }
  float mu[4], rs[4];
  #pragma unroll
  for (int j = 0; j < 4; j++){
    mu[j] = s[j]*(1.f/128.f);
    rs[j] = rsqrtf(q[j]*(1.f/128.f) - mu[j]*mu[j] + 1e-5f);
  }
  size_t g = (size_t)b*HW + p0;
  *(float4*)&ws[OFF_MU1 + g]   = make_float4(mu[0],mu[1],mu[2],mu[3]);
  *(float4*)&ws[OFF_RSTD1 + g] = make_float4(rs[0],rs[1],rs[2],rs[3]);
}

// split-bf16 MFMA GEMM, 512 threads, BK=64 double-buffered + pipelined.
// dst[m][p] = LN-epilogue( sum_k A[m][k]*src[k][p] ), optional GELU.
template<bool GELU>
__global__ __launch_bounds__(512,4) void k_gemm_mfma(
    const float* __restrict__ src, int src_bstride,
    const unsigned short* __restrict__ Ahi, const unsigned short* __restrict__ Alo,
    const float* __restrict__ rowsum, const float* __restrict__ bias,
    const float* __restrict__ mu, const float* __restrict__ rstd,
    float* __restrict__ dst, int dst_coff)
{
  __shared__ unsigned short BsH[2][8192];
  __shared__ unsigned short BsL[2][8192];
  int t = threadIdx.x;
  int m0 = blockIdx.x*128, p0 = blockIdx.y*128, b = blockIdx.z;
  int px0 = (t&63)<<1, kb0 = t>>6;          // staging: 2 px, 8 k-rows
  int lane = t&63, wv = t>>6;
  int wm = (wv&3)*32, wn = (wv>>2)*64;
  int colg = lane&15, kg = lane>>4;
  float2 rv[8];
  const float* sbase = src + ((size_t)b*src_bstride)*HW + p0 + px0;

  auto loadreg = [&](int h){
    const float* sp = sbase + ((size_t)(h*64 + kb0*8))*HW;
    #pragma unroll
    for (int e = 0; e < 8; e++) rv[e] = *(const float2*)(sp + (size_t)e*HW);
  };
  auto convstore = [&](int bi){
    #pragma unroll
    for (int j = 0; j < 2; j++){
      int p = px0 + j;
      short8v hv, lv;
      #pragma unroll
      for (int e = 0; e < 8; e++){
        float v = (j==0) ? rv[e].x : rv[e].y;
        unsigned short hh = bf16rn(v);
        hv[e] = (short)hh; lv[e] = (short)bf16rn(v - bf2f(hh));
      }
      int o = (p<<6) + ((kb0 ^ (p&7))<<3);
      *(short8v*)&BsH[bi][o] = hv;
      *(short8v*)&BsL[bi][o] = lv;
    }
  };

  floatx4 acc[2][4];
  #pragma unroll
  for (int i = 0; i < 2; i++)
    #pragma unroll
    for (int j = 0; j < 4; j++) acc[i][j] = (floatx4){0.f,0.f,0.f,0.f};

  auto mfmah = [&](int bi, int h){
    #pragma unroll
    for (int kt = 0; kt < 2; kt++){
      int kb = kt*32 + kg*8;
      short8v ah[2], al[2], bh[4], bl[4];
      #pragma unroll
      for (int f = 0; f < 2; f++){
        size_t arow = (size_t)(m0 + wm + f*16 + colg)*128 + h*64 + kb;
        ah[f] = *(const short8v*)(Ahi + arow);
        al[f] = *(const short8v*)(Alo + arow);
      }
      #pragma unroll
      for (int f = 0; f < 4; f++){
        int p = wn + f*16 + colg;
        int o = (p<<6) + ((((kb>>3) ^ (p&7)))<<3);
        bh[f] = *(const short8v*)&BsH[bi][o];
        bl[f] = *(const short8v*)&BsL[bi][o];
      }
      #pragma unroll
      for (int i = 0; i < 2; i++)
        #pragma unroll
        for (int j = 0; j < 4; j++){
          acc[i][j] = __builtin_amdgcn_mfma_f32_16x16x32_bf16(al[i], bh[j], acc[i][j], 0,0,0);
          acc[i][j] = __builtin_amdgcn_mfma_f32_16x16x32_bf16(ah[i], bl[j], acc[i][j], 0,0,0);
          acc[i][j] = __builtin_amdgcn_mfma_f32_16x16x32_bf16(ah[i], bh[j], acc[i][j], 0,0,0);
        }
    }
  };

  loadreg(0); convstore(0);
  __syncthreads();
  loadreg(1);                 // loads for half 1 in flight under MFMA of half 0
  mfmah(0, 0);
  convstore(1);
  __syncthreads();
  mfmah(1, 1);

  int rowg = kg*4;
  const float* mub = mu   + (size_t)b*HW + p0;
  const float* rsb = rstd + (size_t)b*HW + p0;
  #pragma unroll
  for (int j = 0; j < 4; j++){
    int pc = wn + j*16 + colg;
    float muv = mub[pc], rsv = rsb[pc];
    #pragma unroll
    for (int i = 0; i < 2; i++){
      int mbase = m0 + wm + i*16 + rowg;
      float4 rs4 = *(const float4*)&rowsum[mbase];
      float4 bi4 = *(const float4*)&bias[mbase];
      float rsa[4] = {rs4.x,rs4.y,rs4.z,rs4.w};
      float bia[4] = {bi4.x,bi4.y,bi4.z,bi4.w};
      #pragma unroll
      for (int e = 0; e < 4; e++){
        float v = rsv*(acc[i][j][e] - muv*rsa[e]) + bia[e];
        if (GELU) v = gelu_f(v);
        dst[((size_t)(b*384 + dst_coff + mbase + e))*HW + p0 + pc] = v;
      }
    }
  }
}

// streaming depthwise 3x3 (pad 1)
template<bool GELU, bool SSQ>
__global__ __launch_bounds__(256) void k_dw(const float* __restrict__ src,
                                            const float* __restrict__ wdw,
                                            float* __restrict__ dst,
                                            float* __restrict__ ssq, int ssq_off){
  __shared__ float rows[10][194];
  __shared__ float wred[4];
  int t = threadIdx.x;
  int band = blockIdx.x, c = blockIdx.y, b = blockIdx.z;
  const float* sp = src + ((size_t)(b*384 + c))*HW;
  float w[9];
  #pragma unroll
  for (int j = 0; j < 9; j++) w[j] = wdw[c*9 + j];
  int r0 = band*8;
  for (int e = t; e < 1920; e += 256){
    int r = e/192, cc = e - r*192;
    int gr = r0 + r - 1;
    rows[r][cc+1] = (gr >= 0 && gr < IMG) ? sp[gr*IMG + cc] : 0.f;
  }
  if (t < 20) rows[t>>1][(t&1)*193] = 0.f;
  __syncthreads();
  float s2 = 0.f;
  float* dp = dst + ((size_t)(b*384 + c))*HW + r0*IMG;
  #pragma unroll
  for (int i = 0; i < 6; i++){
    int px = i*256 + t;
    int r = px/192, cc = px - r*192;
    float v = 0.f;
    #pragma unroll
    for (int dy = 0; dy < 3; dy++)
      #pragma unroll
      for (int dx = 0; dx < 3; dx++)
        v += rows[r+dy][cc+dx] * w[dy*3+dx];
    if (GELU) v = gelu_f(v);
    dp[px] = v;
    if (SSQ) s2 += v*v;
  }
  if (SSQ){
    #pragma unroll
    for (int off = 32; off; off >>= 1) s2 += __shfl_xor(s2, off);
    if ((t & 63) == 0) wred[t>>6] = s2;
    __syncthreads();
    if (t == 0) atomicAdd(&ssq[b*256 + ssq_off + c], wred[0]+wred[1]+wred[2]+wred[3]);
  }
}

// split-K 64x64 gram (fp32): part = sum over 576 px of q2[c][p]*k2[d][p]
__global__ __launch_bounds__(256,4) void k_qk(const float* __restrict__ buf,
                                              float* __restrict__ part){
  __shared__ float qs[64][68];
  __shared__ float ks[64][68];
  int t = threadIdx.x;
  int chunk = blockIdx.x, h = blockIdx.y, b = blockIdx.z;
  int tc = (t>>4)<<2, td = (t&15)<<2;
  int c = t>>2, pq = (t&3)<<4;
  const float* qp = buf + ((size_t)(b*384 + 256 + h*64 + c))*HW + chunk*576 + pq;
  const float* kp = buf + ((size_t)(b*384 +       h*64 + c))*HW + chunk*576 + pq;
  float acc[4][4] = {};
  for (int st = 0; st < 9; st++){
    __syncthreads();
    #pragma unroll
    for (int u = 0; u < 4; u++){
      float4 qv = *(const float4*)(qp + st*64 + u*4);
      float4 kv = *(const float4*)(kp + st*64 + u*4);
      int p = pq + u*4;
      qs[p+0][c] = qv.x; qs[p+1][c] = qv.y; qs[p+2][c] = qv.z; qs[p+3][c] = qv.w;
      ks[p+0][c] = kv.x; ks[p+1][c] = kv.y; ks[p+2][c] = kv.z; ks[p+3][c] = kv.w;
    }
    __syncthreads();
    #pragma unroll 4
    for (int p = 0; p < 64; p++){
      float4 q4 = *(const float4*)&qs[p][tc];
      float4 k4 = *(const float4*)&ks[p][td];
      float qa[4] = {q4.x,q4.y,q4.z,q4.w};
      float ka[4] = {k4.x,k4.y,k4.z,k4.w};
      #pragma unroll
      for (int i = 0; i < 4; i++)
        #pragma unroll
        for (int j = 0; j < 4; j++) acc[i][j] += qa[i]*ka[j];
    }
  }
  float* pp = part + ((size_t)((b*2+h)*64 + chunk))*4096;
  #pragma unroll
  for (int i = 0; i < 4; i++)
    *(float4*)&pp[(tc+i)*64 + td] = make_float4(acc[i][0],acc[i][1],acc[i][2],acc[i][3]);
}

__global__ __launch_bounds__(256) void k_softmax(const float* __restrict__ part,
                                                 const float* __restrict__ ssq,
                                                 const float* __restrict__ scale,
                                                 float* __restrict__ ws_a,
                                                 float* __restrict__ out)
{
  __shared__ float red[8][64];
  __shared__ float rnk[64];
  int t = threadIdx.x;
  int c0 = blockIdx.x*8, h = blockIdx.y, b = blockIdx.z;
  int bh = b*2 + h;
  const float* pp = part + (size_t)bh*64*4096;
  for (int e = t; e < 512; e += 256){
    int c = e>>6, d = e&63;
    float s = 0.f;
    for (int ch = 0; ch < 64; ch++) s += pp[(size_t)ch*4096 + (c0+c)*64 + d];
    red[c][d] = s;
  }
  if (t < 64) rnk[t] = 1.0f/fmaxf(sqrtf(ssq[b*256 + 128 + h*64 + t]), 1e-12f);
  __syncthreads();
  if (t < 8){
    int c = c0 + t;
    float rq = (1.0f/fmaxf(sqrtf(ssq[b*256 + h*64 + c]), 1e-12f))*scale[h];
    float vals[64], vmax = -1e30f;
    for (int d = 0; d < 64; d++){
      float v = red[t][d]*rq*rnk[d];
      vals[d] = v; vmax = fmaxf(vmax, v);
    }
    float* aw = out + 512 + ((size_t)(b*128 + h*64 + c))*64;
    for (int d = 0; d < 64; d++) aw[d] = vals[d];
    float se = 0.f;
    for (int d = 0; d < 64; d++){ float e = expf(vals[d]-vmax); vals[d] = e; se += e; }
    float inv = 1.0f/se;
    float* ar = ws_a + ((size_t)(b*128 + h*64 + c))*64;
    for (int d = 0; d < 64; d++) ar[d] = vals[d]*inv;
  }
}

// out = a @ v2 (block-diag per head) + per-pixel LN stats
__global__ __launch_bounds__(256,2) void k_av(const float* __restrict__ ws_a,
                                              const float* __restrict__ buf,
                                              float* __restrict__ dst,
                                              float* __restrict__ mu2,
                                              float* __restrict__ rstd2)
{
  __shared__ float a_t[64][128];
  __shared__ float v_l[128][64];
  int t = threadIdx.x;
  int pt = blockIdx.x, b = blockIdx.y;
  int p0 = pt*64;
  {
    int c = t>>1, dh = (t&1)<<5;
    const float* ap = ws_a + ((size_t)(b*128 + c))*64 + dh;
    #pragma unroll
    for (int u = 0; u < 8; u++){
      float4 v = *(const float4*)(ap + u*4);
      int d = dh + u*4;
      a_t[d+0][c] = v.x; a_t[d+1][c] = v.y; a_t[d+2][c] = v.z; a_t[d+3][c] = v.w;
    }
    const float* vp = buf + ((size_t)(b*384 + 256 + c))*HW + p0 + dh;
    #pragma unroll
    for (int u = 0; u < 8; u++)
      *(float4*)&v_l[c][dh + u*4] = *(const float4*)(vp + u*4);
  }
  __syncthreads();
  int tm = (t>>4)<<3, tp = (t&15)<<2;
  int hd = tm>>6;
  float acc[8][4] = {};
  #pragma unroll 2
  for (int d = 0; d < 64; d++){
    float4 v4 = *(const float4*)&v_l[hd*64+d][tp];
    float vv[4] = {v4.x,v4.y,v4.z,v4.w};
    #pragma unroll
    for (int i = 0; i < 8; i++){
      float av = a_t[d][tm+i];
      #pragma unroll
      for (int j = 0; j < 4; j++) acc[i][j] += av*vv[j];
    }
  }
  #pragma unroll
  for (int i = 0; i < 8; i++)
    *(float4*)(dst + ((size_t)(b*384 + tm+i))*HW + p0 + tp)
        = make_float4(acc[i][0],acc[i][1],acc[i][2],acc[i][3]);
  __syncthreads();
  float* px = &a_t[0][0];
  if (t < 128) px[t] = 0.f;
  __syncthreads();
  #pragma unroll
  for (int j = 0; j < 4; j++){
    float s = 0.f, q = 0.f;
    #pragma unroll
    for (int i = 0; i < 8; i++){ s += acc[i][j]; q += acc[i][j]*acc[i][j]; }
    atomicAdd(&px[tp+j], s);
    atomicAdd(&px[64+tp+j], q);
  }
  __syncthreads();
  if (t < 64){
    float mu  = px[t]*(1.f/128.f);
    float var = px[64+t]*(1.f/128.f) - mu*mu;
    mu2[(size_t)b*HW + p0 + t]   = mu;
    rstd2[(size_t)b*HW + p0 + t] = rsqrtf(var + 1e-5f);
  }
}

// f_out GEMM (K=256) via split-bf16 MFMA, 512 threads, pipelined; pool epilogue
__global__ __launch_bounds__(512,4) void k_fout_mfma(
    const float* __restrict__ bufz,
    const unsigned short* __restrict__ Ahi, const unsigned short* __restrict__ Alo,
    float* __restrict__ avg, unsigned* __restrict__ maxk)
{
  __shared__ unsigned short BsH[2][8192];
  __shared__ unsigned short BsL[2][8192];
  __shared__ float osum[128];
  __shared__ unsigned okey[128];
  int t = threadIdx.x;
  int p0 = blockIdx.x*128, b = blockIdx.y;
  if (t < 128){ osum[t] = 0.f; okey[t] = 0u; }
  int px0 = (t&63)<<1, kb0 = t>>6;
  int lane = t&63, wv = t>>6;
  int wm = (wv&3)*32, wn = (wv>>2)*64;
  int colg = lane&15, kg = lane>>4;
  float2 rv[8];
  const float* sbase = bufz + ((size_t)b*384)*HW + p0 + px0;

  auto loadreg = [&](int h){
    const float* sp = sbase + ((size_t)(h*64 + kb0*8))*HW;
    #pragma unroll
    for (int e = 0; e < 8; e++) rv[e] = *(const float2*)(sp + (size_t)e*HW);
  };
  auto convstore = [&](int bi){
    #pragma unroll
    for (int j = 0; j < 2; j++){
      int p = px0 + j;
      short8v hv, lv;
      #pragma unroll
      for (int e = 0; e < 8; e++){
        float v = (j==0) ? rv[e].x : rv[e].y;
        unsigned short hh = bf16rn(v);
        hv[e] = (short)hh; lv[e] = (short)bf16rn(v - bf2f(hh));
      }
      int o = (p<<6) + ((kb0 ^ (p&7))<<3);
      *(short8v*)&BsH[bi][o] = hv;
      *(short8v*)&BsL[bi][o] = lv;
    }
  };

  floatx4 acc[2][4];
  #pragma unroll
  for (int i = 0; i < 2; i++)
    #pragma unroll
    for (int j = 0; j < 4; j++) acc[i][j] = (floatx4){0.f,0.f,0.f,0.f};

  auto mfmah = [&](int bi, int h){
    #pragma unroll
    for (int kt = 0; kt < 2; kt++){
      int kb = kt*32 + kg*8;
      short8v ah[2], al[2], bh[4], bl[4];
      #pragma unroll
      for (int f = 0; f < 2; f++){
        size_t arow = (size_t)(wm + f*16 + colg)*256 + h*64 + kb;
        ah[f] = *(const short8v*)(Ahi + arow);
        al[f] = *(const short8v*)(Alo + arow);
      }
      #pragma unroll
      for (int f = 0; f < 4; f++){
        int p = wn + f*16 + colg;
        int o = (p<<6) + ((((kb>>3) ^ (p&7)))<<3);
        bh[f] = *(const short8v*)&BsH[bi][o];
        bl[f] = *(const short8v*)&BsL[bi][o];
      }
      #pragma unroll
      for (int i = 0; i < 2; i++)
        #pragma unroll
        for (int j = 0; j < 4; j++){
          acc[i][j] = __builtin_amdgcn_mfma_f32_16x16x32_bf16(al[i], bh[j], acc[i][j], 0,0,0);
          acc[i][j] = __builtin_amdgcn_mfma_f32_16x16x32_bf16(ah[i], bl[j], acc[i][j], 0,0,0);
          acc[i][j] = __builtin_amdgcn_mfma_f32_16x16x32_bf16(ah[i], bh[j], acc[i][j], 0,0,0);
        }
    }
  };

  loadreg(0); convstore(0);
  __syncthreads();
  #pragma unroll
  for (int h = 1; h < 4; h++){
    loadreg(h);
    mfmah((h-1)&1, h-1);
    convstore(h&1);
    __syncthreads();
  }
  mfmah(1, 3);

  int rowg = kg*4;
  #pragma unroll
  for (int i = 0; i < 2; i++){
    #pragma unroll
    for (int e = 0; e < 4; e++){
      float s = 0.f, mx = -1e30f;
      #pragma unroll
      for (int j = 0; j < 4; j++){ float v = acc[i][j][e]; s += v; mx = fmaxf(mx, v); }
      #pragma unroll
      for (int off = 1; off < 16; off <<= 1){
        s += __shfl_xor(s, off);
        mx = fmaxf(mx, __shfl_xor(mx, off));
      }
      if (colg == 0){
        int oc = wm + i*16 + rowg + e;
        atomicAdd(&osum[oc], s);
        atomicMax(&okey[oc], f2key(mx));
      }
    }
  }
  __syncthreads();
  if (t < 128){
    atomicAdd(&avg[b*128+t], osum[t]);
    atomicMax(&maxk[b*128+t], okey[t]);
  }
}

__global__ __launch_bounds__(128) void k_gate(const float* __restrict__ avg,
                                              const unsigned* __restrict__ maxk,
                                              const float* __restrict__ w1, const float* __restrict__ b1,
                                              const float* __restrict__ w2, const float* __restrict__ b2,
                                              float* __restrict__ out)
{
  __shared__ float ap[128], mp[128], h1a[8], h1m[8];
  int t = threadIdx.x, b = blockIdx.x;
  ap[t] = avg[b*128+t]*(1.0f/36864.0f);
  mp[t] = key2f(maxk[b*128+t]);
  __syncthreads();
  if (t < 8){
    float sa = b1[t], sm = b1[t];
    for (int c = 0; c < 128; c++){ float w = w1[t*128+c]; sa += w*ap[c]; sm += w*mp[c]; }
    h1a[t] = fmaxf(sa, 0.f); h1m[t] = fmaxf(sm, 0.f);
  }
  __syncthreads();
  float y = 2.0f*b2[t];
  for (int r = 0; r < 8; r++) y += w2[t*8+r]*(h1a[r]+h1m[r]);
  out[b*128+t] = 1.0f/(1.0f+expf(-y));
}

extern "C" void kernel_launch(void* const* d_in, const int* in_sizes, int n_in,
                              void* d_out, int out_size, void* d_ws, size_t ws_size,
                              hipStream_t stream)
{
  const float* x        = (const float*)d_in[0];
  const float* ln_in_w  = (const float*)d_in[1];
  const float* ln_in_b  = (const float*)d_in[2];
  const float* wq_pw    = (const float*)d_in[3];
  const float* wq_dw    = (const float*)d_in[4];
  const float* wk_pw    = (const float*)d_in[5];
  const float* wk_dw    = (const float*)d_in[6];
  const float* wv_pw    = (const float*)d_in[7];
  const float* wv_dw    = (const float*)d_in[8];
  const float* scale    = (const float*)d_in[9];
  const float* ln_out_w = (const float*)d_in[10];
  const float* ln_out_b = (const float*)d_in[11];
  const float* f1_pw    = (const float*)d_in[12];
  const float* f1_dw    = (const float*)d_in[13];
  const float* f2_pw    = (const float*)d_in[14];
  const float* f2_dw    = (const float*)d_in[15];
  const float* f_out    = (const float*)d_in[16];
  const float* g_w1     = (const float*)d_in[17];
  const float* g_b1     = (const float*)d_in[18];
  const float* g_w2     = (const float*)d_in[19];
  const float* g_b2     = (const float*)d_in[20];
  float* ws  = (float*)d_ws;
  float* out = (float*)d_out;
  float* BUF = ws + OFF_BUF1;
  const unsigned short* aqh = (const unsigned short*)(ws + OFF_AQH);
  const unsigned short* aql = (const unsigned short*)(ws + OFF_AQL);
  const unsigned short* afh = (const unsigned short*)(ws + OFF_AFH);
  const unsigned short* afl = (const unsigned short*)(ws + OFF_AFL);
  const unsigned short* aoh = (const unsigned short*)(ws + OFF_AOH);
  const unsigned short* aol = (const unsigned short*)(ws + OFF_AOL);

  k_init<<<dim3(8), dim3(256), 0, stream>>>(ws);
  k_prep<<<dim3(451), dim3(256), 0, stream>>>(wq_pw, wk_pw, wv_pw, f1_pw, f2_pw, f_out,
                                              ln_in_w, ln_in_b, ln_out_w, ln_out_b, ws);
  k_stats<<<dim3(36,4), dim3(256), 0, stream>>>(x, ws);
  // q1,k1 (LN folded, MFMA) -> slots 0,1
  k_gemm_mfma<false><<<dim3(2,288,4), dim3(512), 0, stream>>>(
      x, 128, aqh, aql, ws+OFF_RS_QKV, ws+OFF_B_QKV,
      ws+OFF_MU1, ws+OFF_RSTD1, BUF, 0);
  // q2 = dw(q1): s0 -> s2 (+ssq); k2 = dw(k1): s1 -> s0 (+ssq)
  k_dw<false,true><<<dim3(24,128,4), dim3(256), 0, stream>>>(
      BUF, wq_dw, BUF + (size_t)256*HW, ws+OFF_SSQ, 0);
  k_dw<false,true><<<dim3(24,128,4), dim3(256), 0, stream>>>(
      BUF + (size_t)128*HW, wk_dw, BUF, ws+OFF_SSQ, 128);
  // gram partials + softmax
  k_qk<<<dim3(64,2,4), dim3(256), 0, stream>>>(BUF, ws+OFF_PART);
  k_softmax<<<dim3(8,2,4), dim3(256), 0, stream>>>(
      ws+OFF_PART, ws+OFF_SSQ, scale, ws+OFF_A, out);
  // v1 -> s1 (MFMA); v2 = dw(v1): s1 -> s2
  k_gemm_mfma<false><<<dim3(1,288,4), dim3(512), 0, stream>>>(
      x, 128, aqh + 256*128, aql + 256*128, ws+OFF_RS_QKV+256, ws+OFF_B_QKV+256,
      ws+OFF_MU1, ws+OFF_RSTD1, BUF, 128);
  k_dw<false,false><<<dim3(24,128,4), dim3(256), 0, stream>>>(
      BUF + (size_t)128*HW, wv_dw, BUF + (size_t)256*HW, nullptr, 0);
  // out = a @ v2 -> s0, + LN2 stats
  k_av<<<dim3(576,4), dim3(256), 0, stream>>>(
      ws+OFF_A, BUF, BUF, ws+OFF_MU2, ws+OFF_RSTD2);
  // FFN 1x1 (LN folded, MFMA) + GELU: out(s0) -> g1(s1), g2(s2)
  k_gemm_mfma<true><<<dim3(2,288,4), dim3(512), 0, stream>>>(
      BUF, 384, afh, afl, ws+OFF_RS_FFN, ws+OFF_B_FFN,
      ws+OFF_MU2, ws+OFF_RSTD2, BUF, 128);
  // z1 = gelu(dw(g1)): s1 -> s0 ; z2 = gelu(dw(g2)): s2 -> s1
  k_dw<true,false><<<dim3(24,128,4), dim3(256), 0, stream>>>(
      BUF + (size_t)128*HW, f1_dw, BUF, nullptr, 0);
  k_dw<true,false><<<dim3(24,128,4), dim3(256), 0, stream>>>(
      BUF + (size_t)256*HW, f2_dw, BUF + (size_t)128*HW, nullptr, 0);
  // f_out GEMM (MFMA) + pools (z1 at ch 0..127, z2 at ch 128..255)
  k_fout_mfma<<<dim3(288,4), dim3(512), 0, stream>>>(
      BUF, aoh, aol, ws+OFF_AVG, (unsigned*)(ws+OFF_MAXK));
  k_gate<<<dim3(4), dim3(128), 0, stream>>>(
      ws+OFF_AVG, (const unsigned*)(ws+OFF_MAXK), g_w1, g_b1, g_w2, g_b2, out);

  (void)in_sizes; (void)n_in; (void)out_size; (void)ws_size;
}